// Round 2
// baseline (3048.490 us; speedup 1.0000x reference)
//
#include <hip/hip_runtime.h>
#include <hip/hip_bf16.h>
#include <math.h>

#define HIDC 64
#define NLAYER 4
#define NG 512
#define M3 768
#define M2 512
#define M1 256
#define NCLS 10
#define EPSV 1e-5f

// bf16 helpers (packed 2xbf16 in a uint32)
__device__ inline unsigned bf16rne(float x){
  unsigned u = __float_as_uint(x);
  return (u + 0x7fffu + ((u >> 16) & 1u)) >> 16;
}
__device__ inline unsigned packbf2(float lo, float hi){
  return bf16rne(lo) | (bf16rne(hi) << 16);
}
__device__ inline float blo(unsigned u){ return __uint_as_float(u << 16); }
__device__ inline float bhi(unsigned u){ return __uint_as_float(u & 0xffff0000u); }

// ---------------- graph build ----------------
__global__ void k_deg(const int* __restrict__ dst, int E, int* __restrict__ degi){
  int e = blockIdx.x*256 + threadIdx.x;
  if (e < E) atomicAdd(&degi[dst[e]], 1);
}

__global__ void k_norm(const int* __restrict__ degi, float* __restrict__ norm, int n){
  int i = blockIdx.x*256 + threadIdx.x;
  if (i < n){ float d = (float)(degi[i] + 1); norm[i] = rsqrtf(d); }
}

__global__ void k_scan_a(const int* __restrict__ degi, int n, int* __restrict__ row_start, int* __restrict__ bsum){
  __shared__ int tmp[256];
  int tid = threadIdx.x; int i = blockIdx.x*256 + tid;
  int v = (i < n) ? degi[i] : 0;
  tmp[tid] = v; __syncthreads();
  for (int ofs = 1; ofs < 256; ofs <<= 1){
    int t = (tid >= ofs) ? tmp[tid-ofs] : 0;
    __syncthreads();
    tmp[tid] += t;
    __syncthreads();
  }
  if (i < n) row_start[i] = tmp[tid] - v;   // block-local exclusive
  if (tid == 255) bsum[blockIdx.x] = tmp[255];
}

__global__ void k_scan_b(int* __restrict__ bsum, int nb){
  __shared__ int tmp[512];
  int tid = threadIdx.x;
  int v = (tid < nb) ? bsum[tid] : 0;
  tmp[tid] = v; __syncthreads();
  for (int ofs = 1; ofs < 512; ofs <<= 1){
    int t = (tid >= ofs) ? tmp[tid-ofs] : 0;
    __syncthreads();
    tmp[tid] += t;
    __syncthreads();
  }
  if (tid < nb) bsum[tid] = tmp[tid] - v;   // exclusive block offsets
}

__global__ void k_scan_c(int* __restrict__ row_start, const int* __restrict__ bsum,
                         int* __restrict__ cursor, int n, int E){
  int i = blockIdx.x*256 + threadIdx.x;
  if (i < n){
    int v = row_start[i] + bsum[blockIdx.x];
    row_start[i] = v;
    cursor[i] = v;
  }
  if (i == 0) row_start[n] = E;
}

__global__ void k_fill(const int* __restrict__ src, const int* __restrict__ dst, int E,
                       int* __restrict__ cursor, int* __restrict__ col){
  int e = blockIdx.x*256 + threadIdx.x;
  if (e < E){
    int d = dst[e];
    int pos = atomicAdd(&cursor[d], 1);
    col[pos] = src[e];
  }
}

// ---------------- node-level GEMM: U(bf16 packed) = (A @ W) * norm[row] ----------------
template<int K>
__global__ __launch_bounds__(256) void k_node_gemm(const float* __restrict__ A, int lda,
      const float* __restrict__ W, const float* __restrict__ norm, unsigned* __restrict__ U32, int n){
  __shared__ float4 Wl[K*16];   // K x 64 floats
  int tid = threadIdx.x;
  const float4* W4 = (const float4*)W;
  for (int idx = tid; idx < K*16; idx += 256) Wl[idx] = W4[idx];
  __syncthreads();
  int r = blockIdx.x*256 + tid;
  if (r >= n) return;
  float acc[64];
  #pragma unroll
  for (int c = 0; c < 64; c++) acc[c] = 0.f;
  const float* Ar = A + (size_t)r * lda;
  for (int k = 0; k < K; k += 4){
    float4 a4 = *(const float4*)(Ar + k);
    #pragma unroll
    for (int kk = 0; kk < 4; kk++){
      float a = (kk==0) ? a4.x : (kk==1) ? a4.y : (kk==2) ? a4.z : a4.w;
      #pragma unroll
      for (int c4 = 0; c4 < 16; c4++){
        float4 w = Wl[(k+kk)*16 + c4];
        acc[c4*4+0] += a * w.x;
        acc[c4*4+1] += a * w.y;
        acc[c4*4+2] += a * w.z;
        acc[c4*4+3] += a * w.w;
      }
    }
  }
  float nr = norm[r];
  uint4* Ur = (uint4*)(U32 + (size_t)r * 32);
  #pragma unroll
  for (int q = 0; q < 8; q++){
    uint4 o;
    o.x = packbf2(acc[q*8+0]*nr, acc[q*8+1]*nr);
    o.y = packbf2(acc[q*8+2]*nr, acc[q*8+3]*nr);
    o.z = packbf2(acc[q*8+4]*nr, acc[q*8+5]*nr);
    o.w = packbf2(acc[q*8+6]*nr, acc[q*8+7]*nr);
    Ur[q] = o;
  }
}

// ---------------- aggregation + fused BN stats ----------------
// AGG[i] = norm[i] * (sum_{e->i} U[src] + U[i])   (conv bias dropped: exactly
// canceled by the training-mode BN mean subtraction that follows)
__global__ __launch_bounds__(256) void k_agg_bn(const unsigned* __restrict__ U32,
    const int* __restrict__ row_start, const int* __restrict__ col,
    const float* __restrict__ norm, float* __restrict__ AGG,
    float* __restrict__ sums, int n){
  __shared__ float r0[256], r1[256], q0[256], q1[256];
  int tid = threadIdx.x;
  int lane = tid & 31;          // channel pair index: channels 2*lane, 2*lane+1
  int grp  = tid >> 5;          // 8 nodes per block (one per 32-lane half-wave)
  int node = blockIdx.x*8 + grp;
  float s0 = 0.f, s1 = 0.f;
  bool valid = (node < n);
  if (valid){
    unsigned u = U32[(size_t)node*32 + lane];   // self-loop term
    s0 = blo(u); s1 = bhi(u);
    int st = row_start[node], en = row_start[node+1];
    int k = st;
    for (; k + 4 <= en; k += 4){
      int j0 = col[k], j1 = col[k+1], j2 = col[k+2], j3 = col[k+3];
      unsigned a = U32[(size_t)j0*32 + lane];
      unsigned b = U32[(size_t)j1*32 + lane];
      unsigned c = U32[(size_t)j2*32 + lane];
      unsigned d = U32[(size_t)j3*32 + lane];
      s0 += blo(a) + blo(b) + blo(c) + blo(d);
      s1 += bhi(a) + bhi(b) + bhi(c) + bhi(d);
    }
    for (; k < en; ++k){
      unsigned a = U32[(size_t)col[k]*32 + lane];
      s0 += blo(a); s1 += bhi(a);
    }
    float nr = norm[node];
    s0 *= nr; s1 *= nr;
    *(float2*)&AGG[(size_t)node*64 + 2*lane] = make_float2(s0, s1);
  }
  r0[tid] = valid ? s0 : 0.f;
  r1[tid] = valid ? s1 : 0.f;
  q0[tid] = valid ? s0*s0 : 0.f;
  q1[tid] = valid ? s1*s1 : 0.f;
  __syncthreads();
  if (tid < 32){
    float S0=0.f, S1=0.f, Q0=0.f, Q1=0.f;
    #pragma unroll
    for (int g = 0; g < 8; g++){
      S0 += r0[g*32+tid]; S1 += r1[g*32+tid];
      Q0 += q0[g*32+tid]; Q1 += q1[g*32+tid];
    }
    atomicAdd(&sums[2*tid],      S0);
    atomicAdd(&sums[2*tid+1],    S1);
    atomicAdd(&sums[64+2*tid],   Q0);
    atomicAdd(&sums[64+2*tid+1], Q1);
  }
}

// ---------------- batchnorm finalize / apply ----------------
__global__ void k_bn_finalize(const float* __restrict__ sums, const float* __restrict__ g,
                              const float* __restrict__ b, float* __restrict__ sc,
                              float* __restrict__ sh, float invn){
  int c = threadIdx.x;
  float mean = sums[c]*invn;
  float var = sums[64+c]*invn - mean*mean;
  var = fmaxf(var, 0.f);
  float s = g[c]*rsqrtf(var + EPSV);
  sc[c] = s;
  sh[c] = b[c] - mean*s;
}

__global__ void k_bn_apply(const float* __restrict__ AGG, const float* __restrict__ sc_,
                           const float* __restrict__ sh_, float* __restrict__ H, int n, int slab){
  int idx = blockIdx.x*256 + threadIdx.x;  // over n*16 float4s
  if (idx >= n*16) return;
  int row = idx >> 4, c4 = idx & 15;
  const float4* A4 = (const float4*)AGG;
  const float4* sc4 = (const float4*)sc_;
  const float4* sh4 = (const float4*)sh_;
  float4 v = A4[idx]; float4 s = sc4[c4]; float4 h = sh4[c4];
  float4 o = make_float4(v.x*s.x + h.x, v.y*s.y + h.y, v.z*s.z + h.z, v.w*s.w + h.w);
  ((float4*)H)[(size_t)row*64 + slab*16 + c4] = o;
}

// ---------------- pooling ----------------
__device__ inline int lowerb(const int* a, int n, int key){
  int lo = 0, hi = n;
  while (lo < hi){ int mid = (lo+hi) >> 1; if (a[mid] < key) lo = mid+1; else hi = mid; }
  return lo;
}

__global__ __launch_bounds__(256) void k_pool(const float* __restrict__ H, const int* __restrict__ batch,
                                              int n, float* __restrict__ Hg){
  int g = blockIdx.x; int c = threadIdx.x;
  int st = lowerb(batch, n, g), en = lowerb(batch, n, g+1);
  float s = 0.f, mx = -INFINITY;
  for (int r = st; r < en; r++){
    float v = H[(size_t)r*256 + c];
    s += v; mx = fmaxf(mx, v);
  }
  int cnt = en - st;
  float avg = s / (float)(cnt > 1 ? cnt : 1);
  float mo = (cnt > 0) ? mx : 0.f;
  Hg[(size_t)g*M3 + c]        = avg;
  Hg[(size_t)g*M3 + 256 + c]  = s;
  Hg[(size_t)g*M3 + 512 + c]  = mo;
}

// ---------------- readout BN ----------------
__global__ void k_bn2(const float* __restrict__ Hg, const float* __restrict__ g,
                      const float* __restrict__ b, float* __restrict__ zsc, float* __restrict__ zsh){
  int c = blockIdx.x; int tid = threadIdx.x;  // 64 threads
  float s1 = 0.f, s2 = 0.f;
  for (int r = tid; r < NG; r += 64){
    float v = Hg[(size_t)r*M3 + c];
    s1 += v; s2 += v*v;
  }
  for (int o = 32; o > 0; o >>= 1){ s1 += __shfl_down(s1, o); s2 += __shfl_down(s2, o); }
  if (tid == 0){
    float mean = s1/(float)NG;
    float var = s2/(float)NG - mean*mean;
    var = fmaxf(var, 0.f);
    float sc = g[c]*rsqrtf(var + EPSV);
    zsc[c] = sc;
    zsh[c] = b[c] - mean*sc;
  }
}

__global__ void k_bnapply2(const float* __restrict__ Hg, const float* __restrict__ zsc,
                           const float* __restrict__ zsh, float* __restrict__ Z){
  int idx = blockIdx.x*256 + threadIdx.x;
  if (idx >= NG*M3) return;
  int c = idx % M3;
  Z[idx] = Hg[idx]*zsc[c] + zsh[c];
}

// ---------------- readout GEMMs: row per blockIdx.y, col per thread ----------------
__global__ void k_rowgemm(const float* __restrict__ A, int K, const float* __restrict__ W, int N,
                          const float* __restrict__ bias, float* __restrict__ out, int relu){
  int r = blockIdx.y;
  int c = blockIdx.x*256 + threadIdx.x;
  if (c >= N) return;
  const float* Ar = A + (size_t)r*K;
  float acc = 0.f;
  for (int k = 0; k < K; k += 4){
    float4 a4 = *(const float4*)(Ar + k);
    acc += a4.x * W[(size_t)k*N + c];
    acc += a4.y * W[(size_t)(k+1)*N + c];
    acc += a4.z * W[(size_t)(k+2)*N + c];
    acc += a4.w * W[(size_t)(k+3)*N + c];
  }
  acc += bias[c];
  if (relu) acc = fmaxf(acc, 0.f);
  out[(size_t)r*N + c] = acc;
}

__global__ void k_logsoftmax(const float* __restrict__ Z, float* __restrict__ out){
  int row = blockIdx.x*256 + threadIdx.x;
  if (row >= NG) return;
  float v[NCLS];
  float m = -INFINITY;
  for (int j = 0; j < NCLS; j++){ v[j] = Z[row*NCLS + j]; m = fmaxf(m, v[j]); }
  float s = 0.f;
  for (int j = 0; j < NCLS; j++) s += expf(v[j] - m);
  float ls = logf(s) + m;
  for (int j = 0; j < NCLS; j++) out[row*NCLS + j] = v[j] - ls;
}

// ---------------- host ----------------
extern "C" void kernel_launch(void* const* d_in, const int* in_sizes, int n_in,
                              void* d_out, int out_size, void* d_ws, size_t ws_size,
                              hipStream_t stream){
  const float* x    = (const float*)d_in[0];
  const int*   src  = (const int*)d_in[1];
  const int*   dst  = (const int*)d_in[2];
  const int*   batch= (const int*)d_in[3];
  const float* W0   = (const float*)d_in[4];
  const float* Wsm  = (const float*)d_in[5];
  const float* g_bn = (const float*)d_in[7];
  const float* b_bn = (const float*)d_in[8];
  const float* g_out= (const float*)d_in[9];
  const float* b_out= (const float*)d_in[10];
  const float* w1   = (const float*)d_in[11];
  const float* b1   = (const float*)d_in[12];
  const float* w2   = (const float*)d_in[13];
  const float* b2   = (const float*)d_in[14];
  const float* w3   = (const float*)d_in[15];
  const float* b3   = (const float*)d_in[16];

  int n = in_sizes[3];   // N_NODES
  int E = in_sizes[1];   // N_EDGES

  char* ws = (char*)d_ws;
  size_t off = 0;
  auto alloc = [&](size_t bytes) -> char* {
    char* p = ws + off;
    off += (bytes + 255) / 256 * 256;
    return p;
  };
  int*   degi      = (int*)  alloc((size_t)n*4);
  float* normv     = (float*)alloc((size_t)n*4);
  int*   row_start = (int*)  alloc((size_t)(n+1)*4);
  int*   cursor    = (int*)  alloc((size_t)n*4);
  int*   colA      = (int*)  alloc((size_t)E*4);
  int*   bsum      = (int*)  alloc(512*4);
  unsigned* U32    = (unsigned*)alloc((size_t)n*32*4);   // packed bf16, 128B/row
  float* AGG       = (float*)alloc((size_t)n*64*4);
  float* H         = (float*)alloc((size_t)n*256*4);
  float* bnsums    = (float*)alloc(128*4);
  float* bnsc      = (float*)alloc(64*4);
  float* bnsh      = (float*)alloc(64*4);
  float* Hg        = (float*)alloc((size_t)NG*M3*4);
  float* Zbn       = (float*)alloc((size_t)NG*M3*4);
  float* Z1        = (float*)alloc((size_t)NG*M2*4);
  float* Z2        = (float*)alloc((size_t)NG*M1*4);
  float* Z3        = (float*)alloc((size_t)NG*NCLS*4);
  float* zsc       = (float*)alloc(M3*4);
  float* zsh       = (float*)alloc(M3*4);

  int nb256 = (n + 255) / 256;
  int eb256 = (E + 255) / 256;

  hipMemsetAsync(degi, 0, (size_t)n*4, stream);
  k_deg<<<eb256, 256, 0, stream>>>(dst, E, degi);
  k_norm<<<nb256, 256, 0, stream>>>(degi, normv, n);
  k_scan_a<<<nb256, 256, 0, stream>>>(degi, n, row_start, bsum);
  k_scan_b<<<1, 512, 0, stream>>>(bsum, nb256);
  k_scan_c<<<nb256, 256, 0, stream>>>(row_start, bsum, cursor, n, E);
  k_fill<<<eb256, 256, 0, stream>>>(src, dst, E, cursor, colA);

  float invn = 1.f / (float)n;
  for (int l = 0; l < NLAYER; l++){
    if (l == 0)
      k_node_gemm<128><<<nb256, 256, 0, stream>>>(x, 128, W0, normv, U32, n);
    else
      k_node_gemm<64><<<nb256, 256, 0, stream>>>(H + (size_t)(l-1)*64, 256,
                                                 Wsm + (size_t)(l-1)*64*64, normv, U32, n);
    hipMemsetAsync(bnsums, 0, 128*4, stream);
    k_agg_bn<<<(n+7)/8, 256, 0, stream>>>(U32, row_start, colA, normv, AGG, bnsums, n);
    k_bn_finalize<<<1, 64, 0, stream>>>(bnsums, g_bn + l*64, b_bn + l*64, bnsc, bnsh, invn);
    k_bn_apply<<<(n*16 + 255)/256, 256, 0, stream>>>(AGG, bnsc, bnsh, H, n, l);
  }

  k_pool<<<NG, 256, 0, stream>>>(H, batch, n, Hg);
  k_bn2<<<M3, 64, 0, stream>>>(Hg, g_out, b_out, zsc, zsh);
  k_bnapply2<<<(NG*M3 + 255)/256, 256, 0, stream>>>(Hg, zsc, zsh, Zbn);

  { dim3 g1((M2 + 255)/256, NG); k_rowgemm<<<g1, 256, 0, stream>>>(Zbn, M3, w1, M2, b1, Z1, 1); }
  { dim3 g2((M1 + 255)/256, NG); k_rowgemm<<<g2, 256, 0, stream>>>(Z1, M2, w2, M1, b2, Z2, 1); }
  { dim3 g3(1, NG);              k_rowgemm<<<g3, 256, 0, stream>>>(Z2, M1, w3, NCLS, b3, Z3, 0); }

  k_logsoftmax<<<(NG + 255)/256, 256, 0, stream>>>(Z3, (float*)d_out);
}

// Round 3
// 914.946 us; speedup vs baseline: 3.3319x; 3.3319x over previous
//
#include <hip/hip_runtime.h>
#include <hip/hip_bf16.h>
#include <math.h>

#define HIDC 64
#define NLAYER 4
#define NG 512
#define M3 768
#define M2 512
#define M1 256
#define NCLS 10
#define EPSV 1e-5f

// bf16 helpers (packed 2xbf16 in a uint32)
__device__ inline unsigned bf16rne(float x){
  unsigned u = __float_as_uint(x);
  return (u + 0x7fffu + ((u >> 16) & 1u)) >> 16;
}
__device__ inline unsigned packbf2(float lo, float hi){
  return bf16rne(lo) | (bf16rne(hi) << 16);
}
__device__ inline float blo(unsigned u){ return __uint_as_float(u << 16); }
__device__ inline float bhi(unsigned u){ return __uint_as_float(u & 0xffff0000u); }

// ---------------- graph build ----------------
__global__ void k_deg(const int* __restrict__ dst, int E, int* __restrict__ degi){
  int e = blockIdx.x*256 + threadIdx.x;
  if (e < E) atomicAdd(&degi[dst[e]], 1);
}

__global__ void k_norm(const int* __restrict__ degi, float* __restrict__ norm, int n){
  int i = blockIdx.x*256 + threadIdx.x;
  if (i < n){ float d = (float)(degi[i] + 1); norm[i] = rsqrtf(d); }
}

__global__ void k_scan_a(const int* __restrict__ degi, int n, int* __restrict__ row_start, int* __restrict__ bsum){
  __shared__ int tmp[256];
  int tid = threadIdx.x; int i = blockIdx.x*256 + tid;
  int v = (i < n) ? degi[i] : 0;
  tmp[tid] = v; __syncthreads();
  for (int ofs = 1; ofs < 256; ofs <<= 1){
    int t = (tid >= ofs) ? tmp[tid-ofs] : 0;
    __syncthreads();
    tmp[tid] += t;
    __syncthreads();
  }
  if (i < n) row_start[i] = tmp[tid] - v;   // block-local exclusive
  if (tid == 255) bsum[blockIdx.x] = tmp[255];
}

__global__ void k_scan_b(int* __restrict__ bsum, int nb){
  __shared__ int tmp[512];
  int tid = threadIdx.x;
  int v = (tid < nb) ? bsum[tid] : 0;
  tmp[tid] = v; __syncthreads();
  for (int ofs = 1; ofs < 512; ofs <<= 1){
    int t = (tid >= ofs) ? tmp[tid-ofs] : 0;
    __syncthreads();
    tmp[tid] += t;
    __syncthreads();
  }
  if (tid < nb) bsum[tid] = tmp[tid] - v;   // exclusive block offsets
}

__global__ void k_scan_c(int* __restrict__ row_start, const int* __restrict__ bsum,
                         int* __restrict__ cursor, int n, int E){
  int i = blockIdx.x*256 + threadIdx.x;
  if (i < n){
    int v = row_start[i] + bsum[blockIdx.x];
    row_start[i] = v;
    cursor[i] = v;
  }
  if (i == 0) row_start[n] = E;
}

__global__ void k_fill(const int* __restrict__ src, const int* __restrict__ dst, int E,
                       int* __restrict__ cursor, int* __restrict__ col){
  int e = blockIdx.x*256 + threadIdx.x;
  if (e < E){
    int d = dst[e];
    int pos = atomicAdd(&cursor[d], 1);
    col[pos] = src[e];
  }
}

// ---------------- node-level GEMM: U(bf16 packed) = (A @ W) * norm[row] ----------------
template<int K>
__global__ __launch_bounds__(256) void k_node_gemm(const float* __restrict__ A, int lda,
      const float* __restrict__ W, const float* __restrict__ norm, unsigned* __restrict__ U32, int n){
  __shared__ float4 Wl[K*16];   // K x 64 floats
  int tid = threadIdx.x;
  const float4* W4 = (const float4*)W;
  for (int idx = tid; idx < K*16; idx += 256) Wl[idx] = W4[idx];
  __syncthreads();
  int r = blockIdx.x*256 + tid;
  if (r >= n) return;
  float acc[64];
  #pragma unroll
  for (int c = 0; c < 64; c++) acc[c] = 0.f;
  const float* Ar = A + (size_t)r * lda;
  for (int k = 0; k < K; k += 4){
    float4 a4 = *(const float4*)(Ar + k);
    #pragma unroll
    for (int kk = 0; kk < 4; kk++){
      float a = (kk==0) ? a4.x : (kk==1) ? a4.y : (kk==2) ? a4.z : a4.w;
      #pragma unroll
      for (int c4 = 0; c4 < 16; c4++){
        float4 w = Wl[(k+kk)*16 + c4];
        acc[c4*4+0] += a * w.x;
        acc[c4*4+1] += a * w.y;
        acc[c4*4+2] += a * w.z;
        acc[c4*4+3] += a * w.w;
      }
    }
  }
  float nr = norm[r];
  uint4* Ur = (uint4*)(U32 + (size_t)r * 32);
  #pragma unroll
  for (int q = 0; q < 8; q++){
    uint4 o;
    o.x = packbf2(acc[q*8+0]*nr, acc[q*8+1]*nr);
    o.y = packbf2(acc[q*8+2]*nr, acc[q*8+3]*nr);
    o.z = packbf2(acc[q*8+4]*nr, acc[q*8+5]*nr);
    o.w = packbf2(acc[q*8+6]*nr, acc[q*8+7]*nr);
    Ur[q] = o;
  }
}

// ---------------- aggregation ----------------
// One node per WAVE (wave-uniform bounds -> scalar col loads possible).
// The wave's two 32-lane halves process different EDGES of the same node:
// a U row is 128B = 32 lanes x 4B, so one full-wave load serves 2 edges.
// Main loop: 8 edges/iter (4 gathers in flight per half). Combine halves by shfl_xor(32).
// AGG[i] = norm[i] * (sum_{e->i} U[src] + U[i])  (conv bias dropped: canceled by BN mean)
__global__ __launch_bounds__(256) void k_agg(const unsigned* __restrict__ U32,
    const int* __restrict__ row_start, const int* __restrict__ col,
    const float* __restrict__ norm, float* __restrict__ AGG, int n){
  int tid = threadIdx.x;
  int lane = tid & 63;
  int half = lane >> 5;
  int cl = lane & 31;           // channel pair index: channels 2*cl, 2*cl+1
  int node = __builtin_amdgcn_readfirstlane(blockIdx.x*4 + (tid >> 6));
  if (node >= n) return;
  int st = row_start[node], en = row_start[node+1];
  float s0 = 0.f, s1 = 0.f;
  if (half == 0){               // self-loop term, loaded once
    unsigned u = U32[(size_t)node*32 + cl];
    s0 = blo(u); s1 = bhi(u);
  }
  int k = st;
  for (; k + 8 <= en; k += 8){
    const int* cp = col + k + half*4;
    int j0 = cp[0], j1 = cp[1], j2 = cp[2], j3 = cp[3];
    unsigned a = U32[(size_t)j0*32 + cl];
    unsigned b = U32[(size_t)j1*32 + cl];
    unsigned c = U32[(size_t)j2*32 + cl];
    unsigned d = U32[(size_t)j3*32 + cl];
    s0 += blo(a) + blo(b) + blo(c) + blo(d);
    s1 += bhi(a) + bhi(b) + bhi(c) + bhi(d);
  }
  for (int kk = k + half; kk < en; kk += 2){
    unsigned a = U32[(size_t)col[kk]*32 + cl];
    s0 += blo(a); s1 += bhi(a);
  }
  s0 += __shfl_xor(s0, 32);
  s1 += __shfl_xor(s1, 32);
  if (half == 0){
    float nr = norm[node];
    *(float2*)&AGG[(size_t)node*64 + 2*cl] = make_float2(s0*nr, s1*nr);
  }
}

// ---------------- batchnorm over rows ----------------
__global__ void k_bn_stats(const float* __restrict__ AGG, int n, float* __restrict__ sums){
  __shared__ float l1[256], l2[256];
  int tid = threadIdx.x; int c = tid & 63; int grp = tid >> 6;
  float s1 = 0.f, s2 = 0.f;
  for (int r = blockIdx.x*4 + grp; r < n; r += gridDim.x*4){
    float v = AGG[(size_t)r*64 + c];
    s1 += v; s2 += v*v;
  }
  l1[tid] = s1; l2[tid] = s2; __syncthreads();
  if (tid < 64){
    float a1 = l1[tid] + l1[tid+64] + l1[tid+128] + l1[tid+192];
    float a2 = l2[tid] + l2[tid+64] + l2[tid+128] + l2[tid+192];
    atomicAdd(&sums[tid], a1);
    atomicAdd(&sums[64+tid], a2);
  }
}

__global__ void k_bn_finalize(const float* __restrict__ sums, const float* __restrict__ g,
                              const float* __restrict__ b, float* __restrict__ sc,
                              float* __restrict__ sh, float invn){
  int c = threadIdx.x;
  float mean = sums[c]*invn;
  float var = sums[64+c]*invn - mean*mean;
  var = fmaxf(var, 0.f);
  float s = g[c]*rsqrtf(var + EPSV);
  sc[c] = s;
  sh[c] = b[c] - mean*s;
}

__global__ void k_bn_apply(const float* __restrict__ AGG, const float* __restrict__ sc_,
                           const float* __restrict__ sh_, float* __restrict__ H, int n, int slab){
  int idx = blockIdx.x*256 + threadIdx.x;  // over n*16 float4s
  if (idx >= n*16) return;
  int row = idx >> 4, c4 = idx & 15;
  const float4* A4 = (const float4*)AGG;
  const float4* sc4 = (const float4*)sc_;
  const float4* sh4 = (const float4*)sh_;
  float4 v = A4[idx]; float4 s = sc4[c4]; float4 h = sh4[c4];
  float4 o = make_float4(v.x*s.x + h.x, v.y*s.y + h.y, v.z*s.z + h.z, v.w*s.w + h.w);
  ((float4*)H)[(size_t)row*64 + slab*16 + c4] = o;
}

// ---------------- pooling ----------------
__device__ inline int lowerb(const int* a, int n, int key){
  int lo = 0, hi = n;
  while (lo < hi){ int mid = (lo+hi) >> 1; if (a[mid] < key) lo = mid+1; else hi = mid; }
  return lo;
}

__global__ __launch_bounds__(256) void k_pool(const float* __restrict__ H, const int* __restrict__ batch,
                                              int n, float* __restrict__ Hg){
  int g = blockIdx.x; int c = threadIdx.x;
  int st = lowerb(batch, n, g), en = lowerb(batch, n, g+1);
  float s = 0.f, mx = -INFINITY;
  for (int r = st; r < en; r++){
    float v = H[(size_t)r*256 + c];
    s += v; mx = fmaxf(mx, v);
  }
  int cnt = en - st;
  float avg = s / (float)(cnt > 1 ? cnt : 1);
  float mo = (cnt > 0) ? mx : 0.f;
  Hg[(size_t)g*M3 + c]        = avg;
  Hg[(size_t)g*M3 + 256 + c]  = s;
  Hg[(size_t)g*M3 + 512 + c]  = mo;
}

// ---------------- readout BN ----------------
__global__ void k_bn2(const float* __restrict__ Hg, const float* __restrict__ g,
                      const float* __restrict__ b, float* __restrict__ zsc, float* __restrict__ zsh){
  int c = blockIdx.x; int tid = threadIdx.x;  // 64 threads
  float s1 = 0.f, s2 = 0.f;
  for (int r = tid; r < NG; r += 64){
    float v = Hg[(size_t)r*M3 + c];
    s1 += v; s2 += v*v;
  }
  for (int o = 32; o > 0; o >>= 1){ s1 += __shfl_down(s1, o); s2 += __shfl_down(s2, o); }
  if (tid == 0){
    float mean = s1/(float)NG;
    float var = s2/(float)NG - mean*mean;
    var = fmaxf(var, 0.f);
    float sc = g[c]*rsqrtf(var + EPSV);
    zsc[c] = sc;
    zsh[c] = b[c] - mean*sc;
  }
}

__global__ void k_bnapply2(const float* __restrict__ Hg, const float* __restrict__ zsc,
                           const float* __restrict__ zsh, float* __restrict__ Z){
  int idx = blockIdx.x*256 + threadIdx.x;
  if (idx >= NG*M3) return;
  int c = idx % M3;
  Z[idx] = Hg[idx]*zsc[c] + zsh[c];
}

// ---------------- readout GEMMs: row per blockIdx.y, col per thread ----------------
__global__ void k_rowgemm(const float* __restrict__ A, int K, const float* __restrict__ W, int N,
                          const float* __restrict__ bias, float* __restrict__ out, int relu){
  int r = blockIdx.y;
  int c = blockIdx.x*256 + threadIdx.x;
  if (c >= N) return;
  const float* Ar = A + (size_t)r*K;
  float acc = 0.f;
  for (int k = 0; k < K; k += 4){
    float4 a4 = *(const float4*)(Ar + k);
    acc += a4.x * W[(size_t)k*N + c];
    acc += a4.y * W[(size_t)(k+1)*N + c];
    acc += a4.z * W[(size_t)(k+2)*N + c];
    acc += a4.w * W[(size_t)(k+3)*N + c];
  }
  acc += bias[c];
  if (relu) acc = fmaxf(acc, 0.f);
  out[(size_t)r*N + c] = acc;
}

__global__ void k_logsoftmax(const float* __restrict__ Z, float* __restrict__ out){
  int row = blockIdx.x*256 + threadIdx.x;
  if (row >= NG) return;
  float v[NCLS];
  float m = -INFINITY;
  for (int j = 0; j < NCLS; j++){ v[j] = Z[row*NCLS + j]; m = fmaxf(m, v[j]); }
  float s = 0.f;
  for (int j = 0; j < NCLS; j++) s += expf(v[j] - m);
  float ls = logf(s) + m;
  for (int j = 0; j < NCLS; j++) out[row*NCLS + j] = v[j] - ls;
}

// ---------------- host ----------------
extern "C" void kernel_launch(void* const* d_in, const int* in_sizes, int n_in,
                              void* d_out, int out_size, void* d_ws, size_t ws_size,
                              hipStream_t stream){
  const float* x    = (const float*)d_in[0];
  const int*   src  = (const int*)d_in[1];
  const int*   dst  = (const int*)d_in[2];
  const int*   batch= (const int*)d_in[3];
  const float* W0   = (const float*)d_in[4];
  const float* Wsm  = (const float*)d_in[5];
  const float* g_bn = (const float*)d_in[7];
  const float* b_bn = (const float*)d_in[8];
  const float* g_out= (const float*)d_in[9];
  const float* b_out= (const float*)d_in[10];
  const float* w1   = (const float*)d_in[11];
  const float* b1   = (const float*)d_in[12];
  const float* w2   = (const float*)d_in[13];
  const float* b2   = (const float*)d_in[14];
  const float* w3   = (const float*)d_in[15];
  const float* b3   = (const float*)d_in[16];

  int n = in_sizes[3];   // N_NODES
  int E = in_sizes[1];   // N_EDGES

  char* ws = (char*)d_ws;
  size_t off = 0;
  auto alloc = [&](size_t bytes) -> char* {
    char* p = ws + off;
    off += (bytes + 255) / 256 * 256;
    return p;
  };
  int*   degi      = (int*)  alloc((size_t)n*4);
  float* normv     = (float*)alloc((size_t)n*4);
  int*   row_start = (int*)  alloc((size_t)(n+1)*4);
  int*   cursor    = (int*)  alloc((size_t)n*4);
  int*   colA      = (int*)  alloc((size_t)E*4);
  int*   bsum      = (int*)  alloc(512*4);
  unsigned* U32    = (unsigned*)alloc((size_t)n*32*4);   // packed bf16, 128B/row
  float* AGG       = (float*)alloc((size_t)n*64*4);
  float* H         = (float*)alloc((size_t)n*256*4);
  float* bnsums    = (float*)alloc(128*4);
  float* bnsc      = (float*)alloc(64*4);
  float* bnsh      = (float*)alloc(64*4);
  float* Hg        = (float*)alloc((size_t)NG*M3*4);
  float* Zbn       = (float*)alloc((size_t)NG*M3*4);
  float* Z1        = (float*)alloc((size_t)NG*M2*4);
  float* Z2        = (float*)alloc((size_t)NG*M1*4);
  float* Z3        = (float*)alloc((size_t)NG*NCLS*4);
  float* zsc       = (float*)alloc(M3*4);
  float* zsh       = (float*)alloc(M3*4);

  int nb256 = (n + 255) / 256;
  int eb256 = (E + 255) / 256;

  hipMemsetAsync(degi, 0, (size_t)n*4, stream);
  k_deg<<<eb256, 256, 0, stream>>>(dst, E, degi);
  k_norm<<<nb256, 256, 0, stream>>>(degi, normv, n);
  k_scan_a<<<nb256, 256, 0, stream>>>(degi, n, row_start, bsum);
  k_scan_b<<<1, 512, 0, stream>>>(bsum, nb256);
  k_scan_c<<<nb256, 256, 0, stream>>>(row_start, bsum, cursor, n, E);
  k_fill<<<eb256, 256, 0, stream>>>(src, dst, E, cursor, colA);

  float invn = 1.f / (float)n;
  for (int l = 0; l < NLAYER; l++){
    if (l == 0)
      k_node_gemm<128><<<nb256, 256, 0, stream>>>(x, 128, W0, normv, U32, n);
    else
      k_node_gemm<64><<<nb256, 256, 0, stream>>>(H + (size_t)(l-1)*64, 256,
                                                 Wsm + (size_t)(l-1)*64*64, normv, U32, n);
    k_agg<<<(n+3)/4, 256, 0, stream>>>(U32, row_start, colA, normv, AGG, n);
    hipMemsetAsync(bnsums, 0, 128*4, stream);
    k_bn_stats<<<256, 256, 0, stream>>>(AGG, n, bnsums);
    k_bn_finalize<<<1, 64, 0, stream>>>(bnsums, g_bn + l*64, b_bn + l*64, bnsc, bnsh, invn);
    k_bn_apply<<<(n*16 + 255)/256, 256, 0, stream>>>(AGG, bnsc, bnsh, H, n, l);
  }

  k_pool<<<NG, 256, 0, stream>>>(H, batch, n, Hg);
  k_bn2<<<M3, 64, 0, stream>>>(Hg, g_out, b_out, zsc, zsh);
  k_bnapply2<<<(NG*M3 + 255)/256, 256, 0, stream>>>(Hg, zsc, zsh, Zbn);

  { dim3 g1((M2 + 255)/256, NG); k_rowgemm<<<g1, 256, 0, stream>>>(Zbn, M3, w1, M2, b1, Z1, 1); }
  { dim3 g2((M1 + 255)/256, NG); k_rowgemm<<<g2, 256, 0, stream>>>(Z1, M2, w2, M1, b2, Z2, 1); }
  { dim3 g3(1, NG);              k_rowgemm<<<g3, 256, 0, stream>>>(Z2, M1, w3, NCLS, b3, Z3, 0); }

  k_logsoftmax<<<(NG + 255)/256, 256, 0, stream>>>(Z3, (float*)d_out);
}

// Round 4
// 819.075 us; speedup vs baseline: 3.7219x; 1.1170x over previous
//
#include <hip/hip_runtime.h>
#include <hip/hip_bf16.h>
#include <math.h>

#define HIDC 64
#define NLAYER 4
#define NG 512
#define M3 768
#define M2 512
#define M1 256
#define NCLS 10
#define EPSV 1e-5f
#define NXCD 8

// bf16 helpers (packed 2xbf16 in a uint32)
__device__ inline unsigned bf16rne(float x){
  unsigned u = __float_as_uint(x);
  return (u + 0x7fffu + ((u >> 16) & 1u)) >> 16;
}
__device__ inline unsigned packbf2(float lo, float hi){
  return bf16rne(lo) | (bf16rne(hi) << 16);
}
__device__ inline float blo(unsigned u){ return __uint_as_float(u << 16); }
__device__ inline float bhi(unsigned u){ return __uint_as_float(u & 0xffff0000u); }

// ---------------- graph build ----------------
__global__ void k_deg(const int* __restrict__ dst, int E, int* __restrict__ degi){
  int e = blockIdx.x*256 + threadIdx.x;
  if (e < E) atomicAdd(&degi[dst[e]], 1);
}

__global__ void k_norm(const int* __restrict__ degi, float* __restrict__ norm, int n){
  int i = blockIdx.x*256 + threadIdx.x;
  if (i < n){ float d = (float)(degi[i] + 1); norm[i] = rsqrtf(d); }
}

__global__ void k_scan_a(const int* __restrict__ degi, int n, int* __restrict__ row_start, int* __restrict__ bsum){
  __shared__ int tmp[256];
  int tid = threadIdx.x; int i = blockIdx.x*256 + tid;
  int v = (i < n) ? degi[i] : 0;
  tmp[tid] = v; __syncthreads();
  for (int ofs = 1; ofs < 256; ofs <<= 1){
    int t = (tid >= ofs) ? tmp[tid-ofs] : 0;
    __syncthreads();
    tmp[tid] += t;
    __syncthreads();
  }
  if (i < n) row_start[i] = tmp[tid] - v;   // block-local exclusive
  if (tid == 255) bsum[blockIdx.x] = tmp[255];
}

__global__ void k_scan_b(int* __restrict__ bsum, int nb){
  __shared__ int tmp[512];
  int tid = threadIdx.x;
  int v = (tid < nb) ? bsum[tid] : 0;
  tmp[tid] = v; __syncthreads();
  for (int ofs = 1; ofs < 512; ofs <<= 1){
    int t = (tid >= ofs) ? tmp[tid-ofs] : 0;
    __syncthreads();
    tmp[tid] += t;
    __syncthreads();
  }
  if (tid < nb) bsum[tid] = tmp[tid] - v;   // exclusive block offsets
}

__global__ void k_scan_c(int* __restrict__ row_start, const int* __restrict__ bsum,
                         int* __restrict__ cursor, int n, int E){
  int i = blockIdx.x*256 + threadIdx.x;
  if (i < n){
    int v = row_start[i] + bsum[blockIdx.x];
    row_start[i] = v;
    cursor[i] = v;
  }
  if (i == 0) row_start[n] = E;
}

// XCD-windowed CSR fill: window w = blockIdx & 7 covers nodes [w*n/8,(w+1)*n/8).
// CSR col positions for that node range are contiguous, so (with the heuristic
// round-robin block->XCD mapping) each XCD's L2 keeps only its own ~800KB col
// window resident and each dirty line is evicted once. Correct regardless of
// the actual mapping: windows are disjoint, cursor atomics are device-scope.
__global__ void k_fill_x(const int* __restrict__ src, const int* __restrict__ dst, int E, int n,
                         int* __restrict__ cursor, int* __restrict__ col, int chunks){
  int b = blockIdx.x;
  int xcd = b & (NXCD-1);
  int chunk = b >> 3;
  int lo = (int)(((long long)xcd * n) / NXCD);
  int hi = (int)(((long long)(xcd+1) * n) / NXCD);
  int per = (E + chunks - 1) / chunks;
  int e0 = chunk * per;
  int e1 = e0 + per; if (e1 > E) e1 = E;
  for (int e = e0 + threadIdx.x; e < e1; e += 256){
    int d = dst[e];
    if (d >= lo && d < hi){
      int pos = atomicAdd(&cursor[d], 1);
      col[pos] = src[e];
    }
  }
}

// ---------------- node-level GEMM: U(bf16 packed) = (A @ W) * norm[row] ----------------
template<int K>
__global__ __launch_bounds__(256) void k_node_gemm(const float* __restrict__ A, int lda,
      const float* __restrict__ W, const float* __restrict__ norm, unsigned* __restrict__ U32, int n){
  __shared__ float4 Wl[K*16];   // K x 64 floats
  int tid = threadIdx.x;
  const float4* W4 = (const float4*)W;
  for (int idx = tid; idx < K*16; idx += 256) Wl[idx] = W4[idx];
  __syncthreads();
  int r = blockIdx.x*256 + tid;
  if (r >= n) return;
  float acc[64];
  #pragma unroll
  for (int c = 0; c < 64; c++) acc[c] = 0.f;
  const float* Ar = A + (size_t)r * lda;
  for (int k = 0; k < K; k += 4){
    float4 a4 = *(const float4*)(Ar + k);
    #pragma unroll
    for (int kk = 0; kk < 4; kk++){
      float a = (kk==0) ? a4.x : (kk==1) ? a4.y : (kk==2) ? a4.z : a4.w;
      #pragma unroll
      for (int c4 = 0; c4 < 16; c4++){
        float4 w = Wl[(k+kk)*16 + c4];
        acc[c4*4+0] += a * w.x;
        acc[c4*4+1] += a * w.y;
        acc[c4*4+2] += a * w.z;
        acc[c4*4+3] += a * w.w;
      }
    }
  }
  float nr = norm[r];
  uint4* Ur = (uint4*)(U32 + (size_t)r * 32);
  #pragma unroll
  for (int q = 0; q < 8; q++){
    uint4 o;
    o.x = packbf2(acc[q*8+0]*nr, acc[q*8+1]*nr);
    o.y = packbf2(acc[q*8+2]*nr, acc[q*8+3]*nr);
    o.z = packbf2(acc[q*8+4]*nr, acc[q*8+5]*nr);
    o.w = packbf2(acc[q*8+6]*nr, acc[q*8+7]*nr);
    Ur[q] = o;
  }
}

// ---------------- aggregation + fused BN stats ----------------
// One node per WAVE (wave-uniform bounds). Each wave handles 8 sequential nodes,
// accumulating BN sum/sumsq in registers; one block reduction + 128 atomics at
// the end (8 shadow copies of sums to spread same-address contention).
// The wave's two 32-lane halves process different EDGES of the same node
// (U row = 128B = 32 lanes x 4B). Main loop 16 edges/iter (8 gathers/half).
// AGG[i] = norm[i] * (sum_{e->i} U[src] + U[i])  (conv bias dropped: canceled by BN mean)
__global__ __launch_bounds__(256) void k_agg_bn(const unsigned* __restrict__ U32,
    const int* __restrict__ row_start, const int* __restrict__ col,
    const float* __restrict__ norm, float* __restrict__ AGG,
    float* __restrict__ sums8, int n){
  int tid = threadIdx.x;
  int wv = tid >> 6;
  int lane = tid & 63;
  int half = lane >> 5;
  int cl = lane & 31;           // channel pair index: channels 2*cl, 2*cl+1
  float rs0=0.f, rs1=0.f, rq0=0.f, rq1=0.f;   // running stats (half 0 lanes)
  int base = blockIdx.x*32 + wv*8;
  for (int it = 0; it < 8; ++it){
    int node = __builtin_amdgcn_readfirstlane(base + it);
    if (node >= n) break;
    int st = row_start[node], en = row_start[node+1];
    float s0 = 0.f, s1 = 0.f;
    if (half == 0){               // self-loop term
      unsigned u = U32[(size_t)node*32 + cl];
      s0 = blo(u); s1 = bhi(u);
    }
    int k = st;
    for (; k + 16 <= en; k += 16){
      const int* cp = col + k + half*8;
      int j0 = cp[0], j1 = cp[1], j2 = cp[2], j3 = cp[3];
      int j4 = cp[4], j5 = cp[5], j6 = cp[6], j7 = cp[7];
      unsigned a = U32[(size_t)j0*32 + cl];
      unsigned b = U32[(size_t)j1*32 + cl];
      unsigned c = U32[(size_t)j2*32 + cl];
      unsigned d = U32[(size_t)j3*32 + cl];
      unsigned e = U32[(size_t)j4*32 + cl];
      unsigned f = U32[(size_t)j5*32 + cl];
      unsigned g = U32[(size_t)j6*32 + cl];
      unsigned h = U32[(size_t)j7*32 + cl];
      s0 += blo(a) + blo(b) + blo(c) + blo(d) + blo(e) + blo(f) + blo(g) + blo(h);
      s1 += bhi(a) + bhi(b) + bhi(c) + bhi(d) + bhi(e) + bhi(f) + bhi(g) + bhi(h);
    }
    for (int kk = k + half; kk < en; kk += 2){
      unsigned a = U32[(size_t)col[kk]*32 + cl];
      s0 += blo(a); s1 += bhi(a);
    }
    s0 += __shfl_xor(s0, 32);
    s1 += __shfl_xor(s1, 32);
    if (half == 0){
      float nr = norm[node];
      s0 *= nr; s1 *= nr;
      *(float2*)&AGG[(size_t)node*64 + 2*cl] = make_float2(s0, s1);
      rs0 += s0; rs1 += s1; rq0 += s0*s0; rq1 += s1*s1;
    }
  }
  __shared__ float L[4][32][4];
  if (half == 0){ L[wv][cl][0]=rs0; L[wv][cl][1]=rs1; L[wv][cl][2]=rq0; L[wv][cl][3]=rq1; }
  __syncthreads();
  if (tid < 128){
    int c2 = tid & 31, f = tid >> 5;   // f: 0=sum_lo 1=sum_hi 2=sq_lo 3=sq_hi
    float v = L[0][c2][f] + L[1][c2][f] + L[2][c2][f] + L[3][c2][f];
    int addr = ((f >= 2) ? 64 : 0) + 2*c2 + (f & 1);
    atomicAdd(&sums8[(blockIdx.x & 7)*128 + addr], v);
  }
}

// ---------------- batchnorm finalize / apply ----------------
__global__ void k_bn_finalize(const float* __restrict__ sums8, const float* __restrict__ g,
                              const float* __restrict__ b, float* __restrict__ sc,
                              float* __restrict__ sh, float invn){
  int c = threadIdx.x;
  float s1 = 0.f, s2 = 0.f;
  #pragma unroll
  for (int s = 0; s < 8; s++){ s1 += sums8[s*128 + c]; s2 += sums8[s*128 + 64 + c]; }
  float mean = s1*invn;
  float var = s2*invn - mean*mean;
  var = fmaxf(var, 0.f);
  float sv = g[c]*rsqrtf(var + EPSV);
  sc[c] = sv;
  sh[c] = b[c] - mean*sv;
}

__global__ void k_bn_apply(const float* __restrict__ AGG, const float* __restrict__ sc_,
                           const float* __restrict__ sh_, float* __restrict__ H, int n, int slab){
  int idx = blockIdx.x*256 + threadIdx.x;  // over n*16 float4s
  if (idx >= n*16) return;
  int row = idx >> 4, c4 = idx & 15;
  const float4* A4 = (const float4*)AGG;
  const float4* sc4 = (const float4*)sc_;
  const float4* sh4 = (const float4*)sh_;
  float4 v = A4[idx]; float4 s = sc4[c4]; float4 h = sh4[c4];
  float4 o = make_float4(v.x*s.x + h.x, v.y*s.y + h.y, v.z*s.z + h.z, v.w*s.w + h.w);
  ((float4*)H)[(size_t)row*64 + slab*16 + c4] = o;
}

// ---------------- pooling ----------------
__device__ inline int lowerb(const int* a, int n, int key){
  int lo = 0, hi = n;
  while (lo < hi){ int mid = (lo+hi) >> 1; if (a[mid] < key) lo = mid+1; else hi = mid; }
  return lo;
}

__global__ __launch_bounds__(256) void k_pool(const float* __restrict__ H, const int* __restrict__ batch,
                                              int n, float* __restrict__ Hg){
  int g = blockIdx.x; int c = threadIdx.x;
  int st = lowerb(batch, n, g), en = lowerb(batch, n, g+1);
  float s = 0.f, mx = -INFINITY;
  for (int r = st; r < en; r++){
    float v = H[(size_t)r*256 + c];
    s += v; mx = fmaxf(mx, v);
  }
  int cnt = en - st;
  float avg = s / (float)(cnt > 1 ? cnt : 1);
  float mo = (cnt > 0) ? mx : 0.f;
  Hg[(size_t)g*M3 + c]        = avg;
  Hg[(size_t)g*M3 + 256 + c]  = s;
  Hg[(size_t)g*M3 + 512 + c]  = mo;
}

// ---------------- readout BN ----------------
__global__ void k_bn2(const float* __restrict__ Hg, const float* __restrict__ g,
                      const float* __restrict__ b, float* __restrict__ zsc, float* __restrict__ zsh){
  int c = blockIdx.x; int tid = threadIdx.x;  // 64 threads
  float s1 = 0.f, s2 = 0.f;
  for (int r = tid; r < NG; r += 64){
    float v = Hg[(size_t)r*M3 + c];
    s1 += v; s2 += v*v;
  }
  for (int o = 32; o > 0; o >>= 1){ s1 += __shfl_down(s1, o); s2 += __shfl_down(s2, o); }
  if (tid == 0){
    float mean = s1/(float)NG;
    float var = s2/(float)NG - mean*mean;
    var = fmaxf(var, 0.f);
    float sc = g[c]*rsqrtf(var + EPSV);
    zsc[c] = sc;
    zsh[c] = b[c] - mean*sc;
  }
}

__global__ void k_bnapply2(const float* __restrict__ Hg, const float* __restrict__ zsc,
                           const float* __restrict__ zsh, float* __restrict__ Z){
  int idx = blockIdx.x*256 + threadIdx.x;
  if (idx >= NG*M3) return;
  int c = idx % M3;
  Z[idx] = Hg[idx]*zsc[c] + zsh[c];
}

// ---------------- readout GEMMs: row per blockIdx.y, col per thread ----------------
__global__ void k_rowgemm(const float* __restrict__ A, int K, const float* __restrict__ W, int N,
                          const float* __restrict__ bias, float* __restrict__ out, int relu){
  int r = blockIdx.y;
  int c = blockIdx.x*256 + threadIdx.x;
  if (c >= N) return;
  const float* Ar = A + (size_t)r*K;
  float acc = 0.f;
  for (int k = 0; k < K; k += 4){
    float4 a4 = *(const float4*)(Ar + k);
    acc += a4.x * W[(size_t)k*N + c];
    acc += a4.y * W[(size_t)(k+1)*N + c];
    acc += a4.z * W[(size_t)(k+2)*N + c];
    acc += a4.w * W[(size_t)(k+3)*N + c];
  }
  acc += bias[c];
  if (relu) acc = fmaxf(acc, 0.f);
  out[(size_t)r*N + c] = acc;
}

__global__ void k_logsoftmax(const float* __restrict__ Z, float* __restrict__ out){
  int row = blockIdx.x*256 + threadIdx.x;
  if (row >= NG) return;
  float v[NCLS];
  float m = -INFINITY;
  for (int j = 0; j < NCLS; j++){ v[j] = Z[row*NCLS + j]; m = fmaxf(m, v[j]); }
  float s = 0.f;
  for (int j = 0; j < NCLS; j++) s += expf(v[j] - m);
  float ls = logf(s) + m;
  for (int j = 0; j < NCLS; j++) out[row*NCLS + j] = v[j] - ls;
}

// ---------------- host ----------------
extern "C" void kernel_launch(void* const* d_in, const int* in_sizes, int n_in,
                              void* d_out, int out_size, void* d_ws, size_t ws_size,
                              hipStream_t stream){
  const float* x    = (const float*)d_in[0];
  const int*   src  = (const int*)d_in[1];
  const int*   dst  = (const int*)d_in[2];
  const int*   batch= (const int*)d_in[3];
  const float* W0   = (const float*)d_in[4];
  const float* Wsm  = (const float*)d_in[5];
  const float* g_bn = (const float*)d_in[7];
  const float* b_bn = (const float*)d_in[8];
  const float* g_out= (const float*)d_in[9];
  const float* b_out= (const float*)d_in[10];
  const float* w1   = (const float*)d_in[11];
  const float* b1   = (const float*)d_in[12];
  const float* w2   = (const float*)d_in[13];
  const float* b2   = (const float*)d_in[14];
  const float* w3   = (const float*)d_in[15];
  const float* b3   = (const float*)d_in[16];

  int n = in_sizes[3];   // N_NODES
  int E = in_sizes[1];   // N_EDGES

  char* ws = (char*)d_ws;
  size_t off = 0;
  auto alloc = [&](size_t bytes) -> char* {
    char* p = ws + off;
    off += (bytes + 255) / 256 * 256;
    return p;
  };
  int*   degi      = (int*)  alloc((size_t)n*4);
  float* normv     = (float*)alloc((size_t)n*4);
  int*   row_start = (int*)  alloc((size_t)(n+1)*4);
  int*   cursor    = (int*)  alloc((size_t)n*4);
  int*   colA      = (int*)  alloc((size_t)E*4);
  int*   bsum      = (int*)  alloc(512*4);
  unsigned* U32    = (unsigned*)alloc((size_t)n*32*4);   // packed bf16, 128B/row
  float* AGG       = (float*)alloc((size_t)n*64*4);
  float* H         = (float*)alloc((size_t)n*256*4);
  float* bnsums    = (float*)alloc(8*128*4);
  float* bnsc      = (float*)alloc(64*4);
  float* bnsh      = (float*)alloc(64*4);
  float* Hg        = (float*)alloc((size_t)NG*M3*4);
  float* Zbn       = (float*)alloc((size_t)NG*M3*4);
  float* Z1        = (float*)alloc((size_t)NG*M2*4);
  float* Z2        = (float*)alloc((size_t)NG*M1*4);
  float* Z3        = (float*)alloc((size_t)NG*NCLS*4);
  float* zsc       = (float*)alloc(M3*4);
  float* zsh       = (float*)alloc(M3*4);

  int nb256 = (n + 255) / 256;
  int eb256 = (E + 255) / 256;

  hipMemsetAsync(degi, 0, (size_t)n*4, stream);
  k_deg<<<eb256, 256, 0, stream>>>(dst, E, degi);
  k_norm<<<nb256, 256, 0, stream>>>(degi, normv, n);
  k_scan_a<<<nb256, 256, 0, stream>>>(degi, n, row_start, bsum);
  k_scan_b<<<1, 512, 0, stream>>>(bsum, nb256);
  k_scan_c<<<nb256, 256, 0, stream>>>(row_start, bsum, cursor, n, E);
  { int chunks = 256; k_fill_x<<<NXCD*chunks, 256, 0, stream>>>(src, dst, E, n, cursor, colA, chunks); }

  float invn = 1.f / (float)n;
  for (int l = 0; l < NLAYER; l++){
    if (l == 0)
      k_node_gemm<128><<<nb256, 256, 0, stream>>>(x, 128, W0, normv, U32, n);
    else
      k_node_gemm<64><<<nb256, 256, 0, stream>>>(H + (size_t)(l-1)*64, 256,
                                                 Wsm + (size_t)(l-1)*64*64, normv, U32, n);
    hipMemsetAsync(bnsums, 0, 8*128*4, stream);
    k_agg_bn<<<(n+31)/32, 256, 0, stream>>>(U32, row_start, colA, normv, AGG, bnsums, n);
    k_bn_finalize<<<1, 64, 0, stream>>>(bnsums, g_bn + l*64, b_bn + l*64, bnsc, bnsh, invn);
    k_bn_apply<<<(n*16 + 255)/256, 256, 0, stream>>>(AGG, bnsc, bnsh, H, n, l);
  }

  k_pool<<<NG, 256, 0, stream>>>(H, batch, n, Hg);
  k_bn2<<<M3, 64, 0, stream>>>(Hg, g_out, b_out, zsc, zsh);
  k_bnapply2<<<(NG*M3 + 255)/256, 256, 0, stream>>>(Hg, zsc, zsh, Zbn);

  { dim3 g1((M2 + 255)/256, NG); k_rowgemm<<<g1, 256, 0, stream>>>(Zbn, M3, w1, M2, b1, Z1, 1); }
  { dim3 g2((M1 + 255)/256, NG); k_rowgemm<<<g2, 256, 0, stream>>>(Z1, M2, w2, M1, b2, Z2, 1); }
  { dim3 g3(1, NG);              k_rowgemm<<<g3, 256, 0, stream>>>(Z2, M1, w3, NCLS, b3, Z3, 0); }

  k_logsoftmax<<<(NG + 255)/256, 256, 0, stream>>>(Z3, (float*)d_out);
}

// Round 5
// 758.164 us; speedup vs baseline: 4.0209x; 1.0803x over previous
//
#include <hip/hip_runtime.h>
#include <hip/hip_bf16.h>
#include <math.h>

#define HIDC 64
#define NLAYER 4
#define NG 512
#define M3 768
#define M2 512
#define M1 256
#define NCLS 10
#define EPSV 1e-5f
#define NXCD 8

// bf16 helpers (packed 2xbf16 in a uint32)
__device__ inline unsigned bf16rne(float x){
  unsigned u = __float_as_uint(x);
  return (u + 0x7fffu + ((u >> 16) & 1u)) >> 16;
}
__device__ inline unsigned packbf2(float lo, float hi){
  return bf16rne(lo) | (bf16rne(hi) << 16);
}
__device__ inline float blo(unsigned u){ return __uint_as_float(u << 16); }
__device__ inline float bhi(unsigned u){ return __uint_as_float(u & 0xffff0000u); }

// ---------------- graph build ----------------
__global__ void k_deg(const int* __restrict__ dst, int E, int* __restrict__ degi){
  int e = blockIdx.x*256 + threadIdx.x;
  if (e < E) atomicAdd(&degi[dst[e]], 1);
}

__global__ void k_norm(const int* __restrict__ degi, float* __restrict__ norm, int n){
  int i = blockIdx.x*256 + threadIdx.x;
  if (i < n){ float d = (float)(degi[i] + 1); norm[i] = rsqrtf(d); }
}

__global__ void k_scan_a(const int* __restrict__ degi, int n, int* __restrict__ row_start, int* __restrict__ bsum){
  __shared__ int tmp[256];
  int tid = threadIdx.x; int i = blockIdx.x*256 + tid;
  int v = (i < n) ? degi[i] : 0;
  tmp[tid] = v; __syncthreads();
  for (int ofs = 1; ofs < 256; ofs <<= 1){
    int t = (tid >= ofs) ? tmp[tid-ofs] : 0;
    __syncthreads();
    tmp[tid] += t;
    __syncthreads();
  }
  if (i < n) row_start[i] = tmp[tid] - v;   // block-local exclusive
  if (tid == 255) bsum[blockIdx.x] = tmp[255];
}

__global__ void k_scan_b(int* __restrict__ bsum, int nb){
  __shared__ int tmp[512];
  int tid = threadIdx.x;
  int v = (tid < nb) ? bsum[tid] : 0;
  tmp[tid] = v; __syncthreads();
  for (int ofs = 1; ofs < 512; ofs <<= 1){
    int t = (tid >= ofs) ? tmp[tid-ofs] : 0;
    __syncthreads();
    tmp[tid] += t;
    __syncthreads();
  }
  if (tid < nb) bsum[tid] = tmp[tid] - v;   // exclusive block offsets
}

__global__ void k_scan_c(int* __restrict__ row_start, const int* __restrict__ bsum,
                         int* __restrict__ cursor, int n, int E){
  int i = blockIdx.x*256 + threadIdx.x;
  if (i < n){
    int v = row_start[i] + bsum[blockIdx.x];
    row_start[i] = v;
    cursor[i] = v;
  }
  if (i == 0) row_start[n] = E;
}

// XCD-windowed CSR fill (see r3 notes): windows disjoint -> correct under any
// block->XCD mapping; round-robin heuristic keeps each col window in one L2.
__global__ void k_fill_x(const int* __restrict__ src, const int* __restrict__ dst, int E, int n,
                         int* __restrict__ cursor, int* __restrict__ col, int chunks){
  int b = blockIdx.x;
  int xcd = b & (NXCD-1);
  int chunk = b >> 3;
  int lo = (int)(((long long)xcd * n) / NXCD);
  int hi = (int)(((long long)(xcd+1) * n) / NXCD);
  int per = (E + chunks - 1) / chunks;
  int e0 = chunk * per;
  int e1 = e0 + per; if (e1 > E) e1 = E;
  for (int e = e0 + threadIdx.x; e < e1; e += 256){
    int d = dst[e];
    if (d >= lo && d < hi){
      int pos = atomicAdd(&cursor[d], 1);
      col[pos] = src[e];
    }
  }
}

// ---------------- node-level GEMM: U(bf16 packed) = (A @ W) * norm[row] ----------------
template<int K>
__global__ __launch_bounds__(256) void k_node_gemm(const float* __restrict__ A, int lda,
      const float* __restrict__ W, const float* __restrict__ norm, unsigned* __restrict__ U32, int n){
  __shared__ float4 Wl[K*16];   // K x 64 floats
  int tid = threadIdx.x;
  const float4* W4 = (const float4*)W;
  for (int idx = tid; idx < K*16; idx += 256) Wl[idx] = W4[idx];
  __syncthreads();
  int r = blockIdx.x*256 + tid;
  if (r >= n) return;
  float acc[64];
  #pragma unroll
  for (int c = 0; c < 64; c++) acc[c] = 0.f;
  const float* Ar = A + (size_t)r * lda;
  for (int k = 0; k < K; k += 4){
    float4 a4 = *(const float4*)(Ar + k);
    #pragma unroll
    for (int kk = 0; kk < 4; kk++){
      float a = (kk==0) ? a4.x : (kk==1) ? a4.y : (kk==2) ? a4.z : a4.w;
      #pragma unroll
      for (int c4 = 0; c4 < 16; c4++){
        float4 w = Wl[(k+kk)*16 + c4];
        acc[c4*4+0] += a * w.x;
        acc[c4*4+1] += a * w.y;
        acc[c4*4+2] += a * w.z;
        acc[c4*4+3] += a * w.w;
      }
    }
  }
  float nr = norm[r];
  uint4* Ur = (uint4*)(U32 + (size_t)r * 32);
  #pragma unroll
  for (int q = 0; q < 8; q++){
    uint4 o;
    o.x = packbf2(acc[q*8+0]*nr, acc[q*8+1]*nr);
    o.y = packbf2(acc[q*8+2]*nr, acc[q*8+3]*nr);
    o.z = packbf2(acc[q*8+4]*nr, acc[q*8+5]*nr);
    o.w = packbf2(acc[q*8+6]*nr, acc[q*8+7]*nr);
    Ur[q] = o;
  }
}

// ---------------- aggregation + fused BN stats (one node per wave) ----------------
__global__ __launch_bounds__(256) void k_agg_bn(const unsigned* __restrict__ U32,
    const int* __restrict__ row_start, const int* __restrict__ col,
    const float* __restrict__ norm, float* __restrict__ AGG,
    float* __restrict__ sums8, int n){
  int tid = threadIdx.x;
  int wv = tid >> 6;
  int lane = tid & 63;
  int half = lane >> 5;
  int cl = lane & 31;           // channel pair index: channels 2*cl, 2*cl+1
  float rs0=0.f, rs1=0.f, rq0=0.f, rq1=0.f;   // running stats (half 0 lanes)
  int base = blockIdx.x*32 + wv*8;
  for (int it = 0; it < 8; ++it){
    int node = __builtin_amdgcn_readfirstlane(base + it);
    if (node >= n) break;
    int st = row_start[node], en = row_start[node+1];
    float s0 = 0.f, s1 = 0.f;
    if (half == 0){               // self-loop term
      unsigned u = U32[(size_t)node*32 + cl];
      s0 = blo(u); s1 = bhi(u);
    }
    int k = st;
    for (; k + 16 <= en; k += 16){
      const int* cp = col + k + half*8;
      int j0 = cp[0], j1 = cp[1], j2 = cp[2], j3 = cp[3];
      int j4 = cp[4], j5 = cp[5], j6 = cp[6], j7 = cp[7];
      unsigned a = U32[(size_t)j0*32 + cl];
      unsigned b = U32[(size_t)j1*32 + cl];
      unsigned c = U32[(size_t)j2*32 + cl];
      unsigned d = U32[(size_t)j3*32 + cl];
      unsigned e = U32[(size_t)j4*32 + cl];
      unsigned f = U32[(size_t)j5*32 + cl];
      unsigned g = U32[(size_t)j6*32 + cl];
      unsigned h = U32[(size_t)j7*32 + cl];
      s0 += blo(a) + blo(b) + blo(c) + blo(d) + blo(e) + blo(f) + blo(g) + blo(h);
      s1 += bhi(a) + bhi(b) + bhi(c) + bhi(d) + bhi(e) + bhi(f) + bhi(g) + bhi(h);
    }
    for (int kk = k + half; kk < en; kk += 2){
      unsigned a = U32[(size_t)col[kk]*32 + cl];
      s0 += blo(a); s1 += bhi(a);
    }
    s0 += __shfl_xor(s0, 32);
    s1 += __shfl_xor(s1, 32);
    if (half == 0){
      float nr = norm[node];
      s0 *= nr; s1 *= nr;
      *(float2*)&AGG[(size_t)node*64 + 2*cl] = make_float2(s0, s1);
      rs0 += s0; rs1 += s1; rq0 += s0*s0; rq1 += s1*s1;
    }
  }
  __shared__ float L[4][32][4];
  if (half == 0){ L[wv][cl][0]=rs0; L[wv][cl][1]=rs1; L[wv][cl][2]=rq0; L[wv][cl][3]=rq1; }
  __syncthreads();
  if (tid < 128){
    int c2 = tid & 31, f = tid >> 5;   // f: 0=sum_lo 1=sum_hi 2=sq_lo 3=sq_hi
    float v = L[0][c2][f] + L[1][c2][f] + L[2][c2][f] + L[3][c2][f];
    int addr = ((f >= 2) ? 64 : 0) + 2*c2 + (f & 1);
    atomicAdd(&sums8[(blockIdx.x & 7)*128 + addr], v);
  }
}

// ---------------- batchnorm finalize / apply ----------------
__global__ void k_bn_finalize(const float* __restrict__ sums8, const float* __restrict__ g,
                              const float* __restrict__ b, float* __restrict__ sc,
                              float* __restrict__ sh, float invn){
  int c = threadIdx.x;
  float s1 = 0.f, s2 = 0.f;
  #pragma unroll
  for (int s = 0; s < 8; s++){ s1 += sums8[s*128 + c]; s2 += sums8[s*128 + 64 + c]; }
  float mean = s1*invn;
  float var = s2*invn - mean*mean;
  var = fmaxf(var, 0.f);
  float sv = g[c]*rsqrtf(var + EPSV);
  sc[c] = sv;
  sh[c] = b[c] - mean*sv;
}

__global__ void k_bn_apply(const float* __restrict__ AGG, const float* __restrict__ sc_,
                           const float* __restrict__ sh_, float* __restrict__ H, int n, int slab){
  int idx = blockIdx.x*256 + threadIdx.x;  // over n*16 float4s
  if (idx >= n*16) return;
  int row = idx >> 4, c4 = idx & 15;
  const float4* A4 = (const float4*)AGG;
  const float4* sc4 = (const float4*)sc_;
  const float4* sh4 = (const float4*)sh_;
  float4 v = A4[idx]; float4 s = sc4[c4]; float4 h = sh4[c4];
  float4 o = make_float4(v.x*s.x + h.x, v.y*s.y + h.y, v.z*s.z + h.z, v.w*s.w + h.w);
  ((float4*)H)[(size_t)row*64 + slab*16 + c4] = o;
}

// ---------------- pooling ----------------
__device__ inline int lowerb(const int* a, int n, int key){
  int lo = 0, hi = n;
  while (lo < hi){ int mid = (lo+hi) >> 1; if (a[mid] < key) lo = mid+1; else hi = mid; }
  return lo;
}

__global__ __launch_bounds__(256) void k_pool(const float* __restrict__ H, const int* __restrict__ batch,
                                              int n, float* __restrict__ Hg){
  int g = blockIdx.x; int c = threadIdx.x;
  int st = lowerb(batch, n, g), en = lowerb(batch, n, g+1);
  float s = 0.f, mx = -INFINITY;
  for (int r = st; r < en; r++){
    float v = H[(size_t)r*256 + c];
    s += v; mx = fmaxf(mx, v);
  }
  int cnt = en - st;
  float avg = s / (float)(cnt > 1 ? cnt : 1);
  float mo = (cnt > 0) ? mx : 0.f;
  Hg[(size_t)g*M3 + c]        = avg;
  Hg[(size_t)g*M3 + 256 + c]  = s;
  Hg[(size_t)g*M3 + 512 + c]  = mo;
}

// ---------------- readout BN (stats -> scale/shift) ----------------
__global__ void k_bn2(const float* __restrict__ Hg, const float* __restrict__ g,
                      const float* __restrict__ b, float* __restrict__ zsc, float* __restrict__ zsh){
  int c = blockIdx.x; int tid = threadIdx.x;  // 64 threads
  float s1 = 0.f, s2 = 0.f;
  for (int r = tid; r < NG; r += 64){
    float v = Hg[(size_t)r*M3 + c];
    s1 += v; s2 += v*v;
  }
  for (int o = 32; o > 0; o >>= 1){ s1 += __shfl_down(s1, o); s2 += __shfl_down(s2, o); }
  if (tid == 0){
    float mean = s1/(float)NG;
    float var = s2/(float)NG - mean*mean;
    var = fmaxf(var, 0.f);
    float sc = g[c]*rsqrtf(var + EPSV);
    zsc[c] = sc;
    zsh[c] = b[c] - mean*sc;
  }
}

// ---------------- tiled readout GEMM ----------------
// C[M x N] = act(A[M x K] @ W[K x N] + bias), optionally applying the readout
// BN (A*zsc[k]+zsh[k], per K-column) while staging the A tile.
// 32x32 block tile, 256 threads, 2x2 outputs/thread, K-step 32.
// LDS rows padded to 36 floats -> worst case 2-way bank conflicts (free).
__global__ __launch_bounds__(256) void k_gemm_t(const float* __restrict__ A, int K,
    const float* __restrict__ W, int N, const float* __restrict__ bias,
    const float* __restrict__ zsc, const float* __restrict__ zsh,
    float* __restrict__ out, int relu, int applybn){
  __shared__ float As[32][36];
  __shared__ float Bs[32][36];   // transposed: Bs[n][k]
  int tid = threadIdx.x;
  int tx = tid & 15, ty = tid >> 4;
  int rb = blockIdx.y << 5, cb = blockIdx.x << 5;
  int lr = tid >> 3;            // 0..31
  int lk = (tid & 7) << 2;      // 0,4,...,28
  float acc00=0.f, acc01=0.f, acc10=0.f, acc11=0.f;
  for (int k0 = 0; k0 < K; k0 += 32){
    float4 av = *(const float4*)&A[(size_t)(rb+lr)*K + k0 + lk];
    if (applybn){
      av.x = av.x*zsc[k0+lk+0] + zsh[k0+lk+0];
      av.y = av.y*zsc[k0+lk+1] + zsh[k0+lk+1];
      av.z = av.z*zsc[k0+lk+2] + zsh[k0+lk+2];
      av.w = av.w*zsc[k0+lk+3] + zsh[k0+lk+3];
    }
    *(float4*)&As[lr][lk] = av;
    float4 bv = *(const float4*)&W[(size_t)(k0+lr)*N + cb + lk];
    Bs[lk+0][lr] = bv.x;
    Bs[lk+1][lr] = bv.y;
    Bs[lk+2][lr] = bv.z;
    Bs[lk+3][lr] = bv.w;
    __syncthreads();
    #pragma unroll
    for (int kk = 0; kk < 32; kk += 4){
      float4 a0 = *(const float4*)&As[ty][kk];
      float4 a1 = *(const float4*)&As[ty+16][kk];
      float4 b0 = *(const float4*)&Bs[tx][kk];
      float4 b1 = *(const float4*)&Bs[tx+16][kk];
      acc00 += a0.x*b0.x + a0.y*b0.y + a0.z*b0.z + a0.w*b0.w;
      acc01 += a0.x*b1.x + a0.y*b1.y + a0.z*b1.z + a0.w*b1.w;
      acc10 += a1.x*b0.x + a1.y*b0.y + a1.z*b0.z + a1.w*b0.w;
      acc11 += a1.x*b1.x + a1.y*b1.y + a1.z*b1.z + a1.w*b1.w;
    }
    __syncthreads();
  }
  int c0 = cb + tx, c1 = cb + tx + 16;
  float bz0 = bias[c0], bz1 = bias[c1];
  acc00 += bz0; acc01 += bz1; acc10 += bz0; acc11 += bz1;
  if (relu){
    acc00 = fmaxf(acc00, 0.f); acc01 = fmaxf(acc01, 0.f);
    acc10 = fmaxf(acc10, 0.f); acc11 = fmaxf(acc11, 0.f);
  }
  out[(size_t)(rb+ty)*N + c0]      = acc00;
  out[(size_t)(rb+ty)*N + c1]      = acc01;
  out[(size_t)(rb+ty+16)*N + c0]   = acc10;
  out[(size_t)(rb+ty+16)*N + c1]   = acc11;
}

// ---------------- final tiny GEMM (K=256, N=10) fused with log-softmax ----------------
// 64 rows/block, 4 threads split K per row, LDS partial reduce, lane-local softmax.
__global__ __launch_bounds__(256) void k_gemm3_lsm(const float* __restrict__ A,
    const float* __restrict__ W, const float* __restrict__ bias, float* __restrict__ out){
  __shared__ float Wl[M1*NCLS];       // 10 KB
  __shared__ float part[64][4][NCLS]; // 10 KB
  int tid = threadIdx.x;
  for (int i = tid; i < M1*NCLS; i += 256) Wl[i] = W[i];
  __syncthreads();
  int r = blockIdx.x*64 + (tid >> 2);
  int q = tid & 3;
  float acc[NCLS];
  #pragma unroll
  for (int j = 0; j < NCLS; j++) acc[j] = 0.f;
  const float4* A4 = (const float4*)(A + (size_t)r*M1 + q*64);
  for (int kq = 0; kq < 16; kq++){
    float4 a = A4[kq];
    int kb = q*64 + kq*4;
    #pragma unroll
    for (int j = 0; j < NCLS; j++){
      acc[j] += a.x*Wl[(kb+0)*NCLS+j] + a.y*Wl[(kb+1)*NCLS+j]
              + a.z*Wl[(kb+2)*NCLS+j] + a.w*Wl[(kb+3)*NCLS+j];
    }
  }
  #pragma unroll
  for (int j = 0; j < NCLS; j++) part[tid>>2][q][j] = acc[j];
  __syncthreads();
  if (tid < 64){
    int rr = blockIdx.x*64 + tid;
    float v[NCLS]; float m = -INFINITY;
    #pragma unroll
    for (int j = 0; j < NCLS; j++){
      v[j] = part[tid][0][j] + part[tid][1][j] + part[tid][2][j] + part[tid][3][j] + bias[j];
      m = fmaxf(m, v[j]);
    }
    float s = 0.f;
    #pragma unroll
    for (int j = 0; j < NCLS; j++) s += expf(v[j] - m);
    float ls = logf(s) + m;
    #pragma unroll
    for (int j = 0; j < NCLS; j++) out[(size_t)rr*NCLS + j] = v[j] - ls;
  }
}

// ---------------- host ----------------
extern "C" void kernel_launch(void* const* d_in, const int* in_sizes, int n_in,
                              void* d_out, int out_size, void* d_ws, size_t ws_size,
                              hipStream_t stream){
  const float* x    = (const float*)d_in[0];
  const int*   src  = (const int*)d_in[1];
  const int*   dst  = (const int*)d_in[2];
  const int*   batch= (const int*)d_in[3];
  const float* W0   = (const float*)d_in[4];
  const float* Wsm  = (const float*)d_in[5];
  const float* g_bn = (const float*)d_in[7];
  const float* b_bn = (const float*)d_in[8];
  const float* g_out= (const float*)d_in[9];
  const float* b_out= (const float*)d_in[10];
  const float* w1   = (const float*)d_in[11];
  const float* b1   = (const float*)d_in[12];
  const float* w2   = (const float*)d_in[13];
  const float* b2   = (const float*)d_in[14];
  const float* w3   = (const float*)d_in[15];
  const float* b3   = (const float*)d_in[16];

  int n = in_sizes[3];   // N_NODES
  int E = in_sizes[1];   // N_EDGES

  char* ws = (char*)d_ws;
  size_t off = 0;
  auto alloc = [&](size_t bytes) -> char* {
    char* p = ws + off;
    off += (bytes + 255) / 256 * 256;
    return p;
  };
  int*   degi      = (int*)  alloc((size_t)n*4);
  float* normv     = (float*)alloc((size_t)n*4);
  int*   row_start = (int*)  alloc((size_t)(n+1)*4);
  int*   cursor    = (int*)  alloc((size_t)n*4);
  int*   colA      = (int*)  alloc((size_t)E*4);
  int*   bsum      = (int*)  alloc(512*4);
  unsigned* U32    = (unsigned*)alloc((size_t)n*32*4);   // packed bf16, 128B/row
  float* AGG       = (float*)alloc((size_t)n*64*4);
  float* H         = (float*)alloc((size_t)n*256*4);
  float* bnsums    = (float*)alloc(8*128*4);
  float* bnsc      = (float*)alloc(64*4);
  float* bnsh      = (float*)alloc(64*4);
  float* Hg        = (float*)alloc((size_t)NG*M3*4);
  float* Z1        = (float*)alloc((size_t)NG*M2*4);
  float* Z2        = (float*)alloc((size_t)NG*M1*4);
  float* zsc       = (float*)alloc(M3*4);
  float* zsh       = (float*)alloc(M3*4);

  int nb256 = (n + 255) / 256;
  int eb256 = (E + 255) / 256;

  hipMemsetAsync(degi, 0, (size_t)n*4, stream);
  k_deg<<<eb256, 256, 0, stream>>>(dst, E, degi);
  k_norm<<<nb256, 256, 0, stream>>>(degi, normv, n);
  k_scan_a<<<nb256, 256, 0, stream>>>(degi, n, row_start, bsum);
  k_scan_b<<<1, 512, 0, stream>>>(bsum, nb256);
  k_scan_c<<<nb256, 256, 0, stream>>>(row_start, bsum, cursor, n, E);
  { int chunks = 256; k_fill_x<<<NXCD*chunks, 256, 0, stream>>>(src, dst, E, n, cursor, colA, chunks); }

  float invn = 1.f / (float)n;
  for (int l = 0; l < NLAYER; l++){
    if (l == 0)
      k_node_gemm<128><<<nb256, 256, 0, stream>>>(x, 128, W0, normv, U32, n);
    else
      k_node_gemm<64><<<nb256, 256, 0, stream>>>(H + (size_t)(l-1)*64, 256,
                                                 Wsm + (size_t)(l-1)*64*64, normv, U32, n);
    hipMemsetAsync(bnsums, 0, 8*128*4, stream);
    k_agg_bn<<<(n+31)/32, 256, 0, stream>>>(U32, row_start, colA, normv, AGG, bnsums, n);
    k_bn_finalize<<<1, 64, 0, stream>>>(bnsums, g_bn + l*64, b_bn + l*64, bnsc, bnsh, invn);
    k_bn_apply<<<(n*16 + 255)/256, 256, 0, stream>>>(AGG, bnsc, bnsh, H, n, l);
  }

  k_pool<<<NG, 256, 0, stream>>>(H, batch, n, Hg);
  k_bn2<<<M3, 64, 0, stream>>>(Hg, g_out, b_out, zsc, zsh);

  { dim3 g1(M2/32, NG/32); k_gemm_t<<<g1, 256, 0, stream>>>(Hg, M3, w1, M2, b1, zsc, zsh, Z1, 1, 1); }
  { dim3 g2(M1/32, NG/32); k_gemm_t<<<g2, 256, 0, stream>>>(Z1, M2, w2, M1, b2, nullptr, nullptr, Z2, 1, 0); }
  k_gemm3_lsm<<<NG/64, 256, 0, stream>>>(Z2, w3, b3, (float*)d_out);
}

// Round 6
// 723.496 us; speedup vs baseline: 4.2136x; 1.0479x over previous
//
#include <hip/hip_runtime.h>
#include <hip/hip_bf16.h>
#include <math.h>

#define HIDC 64
#define NLAYER 4
#define NG 512
#define M3 768
#define M2 512
#define M1 256
#define NCLS 10
#define EPSV 1e-5f
#define NXCD 8

// bf16 helpers (packed 2xbf16 in a uint32)
__device__ inline unsigned bf16rne(float x){
  unsigned u = __float_as_uint(x);
  return (u + 0x7fffu + ((u >> 16) & 1u)) >> 16;
}
__device__ inline unsigned packbf2(float lo, float hi){
  return bf16rne(lo) | (bf16rne(hi) << 16);
}
__device__ inline float blo(unsigned u){ return __uint_as_float(u << 16); }
__device__ inline float bhi(unsigned u){ return __uint_as_float(u & 0xffff0000u); }

// ---------------- graph build ----------------
__global__ void k_deg(const int* __restrict__ dst, int E, int* __restrict__ degi){
  int e = blockIdx.x*256 + threadIdx.x;
  if (e < E) atomicAdd(&degi[__builtin_nontemporal_load(&dst[e])], 1);
}

__global__ void k_norm(const int* __restrict__ degi, float* __restrict__ norm, int n){
  int i = blockIdx.x*256 + threadIdx.x;
  if (i < n){ float d = (float)(degi[i] + 1); norm[i] = rsqrtf(d); }
}

__global__ void k_scan_a(const int* __restrict__ degi, int n, int* __restrict__ row_start, int* __restrict__ bsum){
  __shared__ int tmp[256];
  int tid = threadIdx.x; int i = blockIdx.x*256 + tid;
  int v = (i < n) ? degi[i] : 0;
  tmp[tid] = v; __syncthreads();
  for (int ofs = 1; ofs < 256; ofs <<= 1){
    int t = (tid >= ofs) ? tmp[tid-ofs] : 0;
    __syncthreads();
    tmp[tid] += t;
    __syncthreads();
  }
  if (i < n) row_start[i] = tmp[tid] - v;   // block-local exclusive
  if (tid == 255) bsum[blockIdx.x] = tmp[255];
}

__global__ void k_scan_b(int* __restrict__ bsum, int nb){
  __shared__ int tmp[512];
  int tid = threadIdx.x;
  int v = (tid < nb) ? bsum[tid] : 0;
  tmp[tid] = v; __syncthreads();
  for (int ofs = 1; ofs < 512; ofs <<= 1){
    int t = (tid >= ofs) ? tmp[tid-ofs] : 0;
    __syncthreads();
    tmp[tid] += t;
    __syncthreads();
  }
  if (tid < nb) bsum[tid] = tmp[tid] - v;   // exclusive block offsets
}

__global__ void k_scan_c(int* __restrict__ row_start, const int* __restrict__ bsum,
                         int* __restrict__ cursor, int n, int E){
  int i = blockIdx.x*256 + threadIdx.x;
  if (i < n){
    int v = row_start[i] + bsum[blockIdx.x];
    row_start[i] = v;
    cursor[i] = v;
  }
  if (i == 0) row_start[n] = E;
}

// XCD-windowed CSR fill. Non-temporal src/dst loads keep the scan from
// evicting the window's col/cursor lines out of L2 (r5 post-mortem: streaming
// fills caused 74MB of write amplification). Windows disjoint -> correct
// under any block->XCD mapping.
__global__ void k_fill_x(const int* __restrict__ src, const int* __restrict__ dst, int E, int n,
                         int* __restrict__ cursor, int* __restrict__ col, int chunks){
  int b = blockIdx.x;
  int xcd = b & (NXCD-1);
  int chunk = b >> 3;
  int lo = (int)(((long long)xcd * n) / NXCD);
  int hi = (int)(((long long)(xcd+1) * n) / NXCD);
  int per = (E + chunks - 1) / chunks;
  int e0 = chunk * per;
  int e1 = e0 + per; if (e1 > E) e1 = E;
  for (int e = e0 + threadIdx.x; e < e1; e += 256){
    int d = __builtin_nontemporal_load(&dst[e]);
    if (d >= lo && d < hi){
      int pos = atomicAdd(&cursor[d], 1);
      col[pos] = __builtin_nontemporal_load(&src[e]);
    }
  }
}

// ---------------- node-level GEMM: U(bf16 packed) = ((A_bn) @ W) * norm[row] --------
// BN=1: A is the previous layer's AGG; the BatchNorm scale/shift (scsh[0:64]=sc,
// scsh[64:128]=sh) is applied to A elements while loading (replaces k_bn_apply).
template<int K, int BN>
__global__ __launch_bounds__(256) void k_node_gemm(const float* __restrict__ A, int lda,
      const float* __restrict__ W, const float* __restrict__ norm,
      const float* __restrict__ scsh, unsigned* __restrict__ U32, int n){
  __shared__ float4 Wl[K*16];   // K x 64 floats
  int tid = threadIdx.x;
  const float4* W4 = (const float4*)W;
  for (int idx = tid; idx < K*16; idx += 256) Wl[idx] = W4[idx];
  __syncthreads();
  int r = blockIdx.x*256 + tid;
  if (r >= n) return;
  float acc[64];
  #pragma unroll
  for (int c = 0; c < 64; c++) acc[c] = 0.f;
  const float* Ar = A + (size_t)r * lda;
  for (int k = 0; k < K; k += 4){
    float4 a4 = *(const float4*)(Ar + k);
    if (BN){
      a4.x = a4.x*scsh[k+0] + scsh[64+k+0];
      a4.y = a4.y*scsh[k+1] + scsh[64+k+1];
      a4.z = a4.z*scsh[k+2] + scsh[64+k+2];
      a4.w = a4.w*scsh[k+3] + scsh[64+k+3];
    }
    #pragma unroll
    for (int kk = 0; kk < 4; kk++){
      float a = (kk==0) ? a4.x : (kk==1) ? a4.y : (kk==2) ? a4.z : a4.w;
      #pragma unroll
      for (int c4 = 0; c4 < 16; c4++){
        float4 w = Wl[(k+kk)*16 + c4];
        acc[c4*4+0] += a * w.x;
        acc[c4*4+1] += a * w.y;
        acc[c4*4+2] += a * w.z;
        acc[c4*4+3] += a * w.w;
      }
    }
  }
  float nr = norm[r];
  uint4* Ur = (uint4*)(U32 + (size_t)r * 32);
  #pragma unroll
  for (int q = 0; q < 8; q++){
    uint4 o;
    o.x = packbf2(acc[q*8+0]*nr, acc[q*8+1]*nr);
    o.y = packbf2(acc[q*8+2]*nr, acc[q*8+3]*nr);
    o.z = packbf2(acc[q*8+4]*nr, acc[q*8+5]*nr);
    o.w = packbf2(acc[q*8+6]*nr, acc[q*8+7]*nr);
    Ur[q] = o;
  }
}

// ---------------- aggregation + fused BN stats (one node per wave) ----------------
__global__ __launch_bounds__(256) void k_agg_bn(const unsigned* __restrict__ U32,
    const int* __restrict__ row_start, const int* __restrict__ col,
    const float* __restrict__ norm, float* __restrict__ AGG,
    float* __restrict__ sums8, int n){
  int tid = threadIdx.x;
  int wv = tid >> 6;
  int lane = tid & 63;
  int half = lane >> 5;
  int cl = lane & 31;           // channel pair index: channels 2*cl, 2*cl+1
  float rs0=0.f, rs1=0.f, rq0=0.f, rq1=0.f;   // running stats (half 0 lanes)
  int base = blockIdx.x*32 + wv*8;
  for (int it = 0; it < 8; ++it){
    int node = __builtin_amdgcn_readfirstlane(base + it);
    if (node >= n) break;
    int st = row_start[node], en = row_start[node+1];
    float s0 = 0.f, s1 = 0.f;
    if (half == 0){               // self-loop term
      unsigned u = U32[(size_t)node*32 + cl];
      s0 = blo(u); s1 = bhi(u);
    }
    int k = st;
    for (; k + 16 <= en; k += 16){
      const int* cp = col + k + half*8;
      int j0 = cp[0], j1 = cp[1], j2 = cp[2], j3 = cp[3];
      int j4 = cp[4], j5 = cp[5], j6 = cp[6], j7 = cp[7];
      unsigned a = U32[(size_t)j0*32 + cl];
      unsigned b = U32[(size_t)j1*32 + cl];
      unsigned c = U32[(size_t)j2*32 + cl];
      unsigned d = U32[(size_t)j3*32 + cl];
      unsigned e = U32[(size_t)j4*32 + cl];
      unsigned f = U32[(size_t)j5*32 + cl];
      unsigned g = U32[(size_t)j6*32 + cl];
      unsigned h = U32[(size_t)j7*32 + cl];
      s0 += blo(a) + blo(b) + blo(c) + blo(d) + blo(e) + blo(f) + blo(g) + blo(h);
      s1 += bhi(a) + bhi(b) + bhi(c) + bhi(d) + bhi(e) + bhi(f) + bhi(g) + bhi(h);
    }
    for (int kk = k + half; kk < en; kk += 2){
      unsigned a = U32[(size_t)col[kk]*32 + cl];
      s0 += blo(a); s1 += bhi(a);
    }
    s0 += __shfl_xor(s0, 32);
    s1 += __shfl_xor(s1, 32);
    if (half == 0){
      float nr = norm[node];
      s0 *= nr; s1 *= nr;
      *(float2*)&AGG[(size_t)node*64 + 2*cl] = make_float2(s0, s1);
      rs0 += s0; rs1 += s1; rq0 += s0*s0; rq1 += s1*s1;
    }
  }
  __shared__ float L[4][32][4];
  if (half == 0){ L[wv][cl][0]=rs0; L[wv][cl][1]=rs1; L[wv][cl][2]=rq0; L[wv][cl][3]=rq1; }
  __syncthreads();
  if (tid < 128){
    int c2 = tid & 31, f = tid >> 5;   // f: 0=sum_lo 1=sum_hi 2=sq_lo 3=sq_hi
    float v = L[0][c2][f] + L[1][c2][f] + L[2][c2][f] + L[3][c2][f];
    int addr = ((f >= 2) ? 64 : 0) + 2*c2 + (f & 1);
    atomicAdd(&sums8[(blockIdx.x & 7)*128 + addr], v);
  }
}

// ---------------- batchnorm finalize: per-layer scale/shift ----------------
// scsh[0:64] = scale, scsh[64:128] = shift for this layer.
__global__ void k_bn_finalize(const float* __restrict__ sums8, const float* __restrict__ g,
                              const float* __restrict__ b, float* __restrict__ scsh, float invn){
  int c = threadIdx.x;
  float s1 = 0.f, s2 = 0.f;
  #pragma unroll
  for (int s = 0; s < 8; s++){ s1 += sums8[s*128 + c]; s2 += sums8[s*128 + 64 + c]; }
  float mean = s1*invn;
  float var = s2*invn - mean*mean;
  var = fmaxf(var, 0.f);
  float sv = g[c]*rsqrtf(var + EPSV);
  scsh[c] = sv;
  scsh[64 + c] = b[c] - mean*sv;
}

// ---------------- pooling (applies per-layer BN scale/shift on the fly) --------
__device__ inline int lowerb(const int* a, int n, int key){
  int lo = 0, hi = n;
  while (lo < hi){ int mid = (lo+hi) >> 1; if (a[mid] < key) lo = mid+1; else hi = mid; }
  return lo;
}

__global__ __launch_bounds__(256) void k_pool(const float* __restrict__ AGGall, size_t lstride,
                                              const float* __restrict__ bnss,
                                              const int* __restrict__ batch,
                                              int n, float* __restrict__ Hg){
  int g = blockIdx.x; int c = threadIdx.x;
  int l = c >> 6, ch = c & 63;
  const float* A = AGGall + (size_t)l * lstride;
  float sc = bnss[l*128 + ch], sh = bnss[l*128 + 64 + ch];
  int st = lowerb(batch, n, g), en = lowerb(batch, n, g+1);
  float s = 0.f, mx = -INFINITY;
  for (int r = st; r < en; r++){
    float v = A[(size_t)r*64 + ch]*sc + sh;
    s += v; mx = fmaxf(mx, v);
  }
  int cnt = en - st;
  float avg = s / (float)(cnt > 1 ? cnt : 1);
  float mo = (cnt > 0) ? mx : 0.f;
  Hg[(size_t)g*M3 + c]        = avg;
  Hg[(size_t)g*M3 + 256 + c]  = s;
  Hg[(size_t)g*M3 + 512 + c]  = mo;
}

// ---------------- readout BN (stats -> scale/shift) ----------------
__global__ void k_bn2(const float* __restrict__ Hg, const float* __restrict__ g,
                      const float* __restrict__ b, float* __restrict__ zsc, float* __restrict__ zsh){
  int c = blockIdx.x; int tid = threadIdx.x;  // 64 threads
  float s1 = 0.f, s2 = 0.f;
  for (int r = tid; r < NG; r += 64){
    float v = Hg[(size_t)r*M3 + c];
    s1 += v; s2 += v*v;
  }
  for (int o = 32; o > 0; o >>= 1){ s1 += __shfl_down(s1, o); s2 += __shfl_down(s2, o); }
  if (tid == 0){
    float mean = s1/(float)NG;
    float var = s2/(float)NG - mean*mean;
    var = fmaxf(var, 0.f);
    float sc = g[c]*rsqrtf(var + EPSV);
    zsc[c] = sc;
    zsh[c] = b[c] - mean*sc;
  }
}

// ---------------- tiled readout GEMM (32x32 tile, 2x2/thread) ----------------
__global__ __launch_bounds__(256) void k_gemm_t(const float* __restrict__ A, int K,
    const float* __restrict__ W, int N, const float* __restrict__ bias,
    const float* __restrict__ zsc, const float* __restrict__ zsh,
    float* __restrict__ out, int relu, int applybn){
  __shared__ float As[32][36];
  __shared__ float Bs[32][36];   // transposed: Bs[n][k]
  int tid = threadIdx.x;
  int tx = tid & 15, ty = tid >> 4;
  int rb = blockIdx.y << 5, cb = blockIdx.x << 5;
  int lr = tid >> 3;            // 0..31
  int lk = (tid & 7) << 2;      // 0,4,...,28
  float acc00=0.f, acc01=0.f, acc10=0.f, acc11=0.f;
  for (int k0 = 0; k0 < K; k0 += 32){
    float4 av = *(const float4*)&A[(size_t)(rb+lr)*K + k0 + lk];
    if (applybn){
      av.x = av.x*zsc[k0+lk+0] + zsh[k0+lk+0];
      av.y = av.y*zsc[k0+lk+1] + zsh[k0+lk+1];
      av.z = av.z*zsc[k0+lk+2] + zsh[k0+lk+2];
      av.w = av.w*zsc[k0+lk+3] + zsh[k0+lk+3];
    }
    *(float4*)&As[lr][lk] = av;
    float4 bv = *(const float4*)&W[(size_t)(k0+lr)*N + cb + lk];
    Bs[lk+0][lr] = bv.x;
    Bs[lk+1][lr] = bv.y;
    Bs[lk+2][lr] = bv.z;
    Bs[lk+3][lr] = bv.w;
    __syncthreads();
    #pragma unroll
    for (int kk = 0; kk < 32; kk += 4){
      float4 a0 = *(const float4*)&As[ty][kk];
      float4 a1 = *(const float4*)&As[ty+16][kk];
      float4 b0 = *(const float4*)&Bs[tx][kk];
      float4 b1 = *(const float4*)&Bs[tx+16][kk];
      acc00 += a0.x*b0.x + a0.y*b0.y + a0.z*b0.z + a0.w*b0.w;
      acc01 += a0.x*b1.x + a0.y*b1.y + a0.z*b1.z + a0.w*b1.w;
      acc10 += a1.x*b0.x + a1.y*b0.y + a1.z*b0.z + a1.w*b0.w;
      acc11 += a1.x*b1.x + a1.y*b1.y + a1.z*b1.z + a1.w*b1.w;
    }
    __syncthreads();
  }
  int c0 = cb + tx, c1 = cb + tx + 16;
  float bz0 = bias[c0], bz1 = bias[c1];
  acc00 += bz0; acc01 += bz1; acc10 += bz0; acc11 += bz1;
  if (relu){
    acc00 = fmaxf(acc00, 0.f); acc01 = fmaxf(acc01, 0.f);
    acc10 = fmaxf(acc10, 0.f); acc11 = fmaxf(acc11, 0.f);
  }
  out[(size_t)(rb+ty)*N + c0]      = acc00;
  out[(size_t)(rb+ty)*N + c1]      = acc01;
  out[(size_t)(rb+ty+16)*N + c0]   = acc10;
  out[(size_t)(rb+ty+16)*N + c1]   = acc11;
}

// ---------------- final tiny GEMM (K=256, N=10) fused with log-softmax --------
__global__ __launch_bounds__(256) void k_gemm3_lsm(const float* __restrict__ A,
    const float* __restrict__ W, const float* __restrict__ bias, float* __restrict__ out){
  __shared__ float Wl[M1*NCLS];       // 10 KB
  __shared__ float part[64][4][NCLS]; // 10 KB
  int tid = threadIdx.x;
  for (int i = tid; i < M1*NCLS; i += 256) Wl[i] = W[i];
  __syncthreads();
  int r = blockIdx.x*64 + (tid >> 2);
  int q = tid & 3;
  float acc[NCLS];
  #pragma unroll
  for (int j = 0; j < NCLS; j++) acc[j] = 0.f;
  const float4* A4 = (const float4*)(A + (size_t)r*M1 + q*64);
  for (int kq = 0; kq < 16; kq++){
    float4 a = A4[kq];
    int kb = q*64 + kq*4;
    #pragma unroll
    for (int j = 0; j < NCLS; j++){
      acc[j] += a.x*Wl[(kb+0)*NCLS+j] + a.y*Wl[(kb+1)*NCLS+j]
              + a.z*Wl[(kb+2)*NCLS+j] + a.w*Wl[(kb+3)*NCLS+j];
    }
  }
  #pragma unroll
  for (int j = 0; j < NCLS; j++) part[tid>>2][q][j] = acc[j];
  __syncthreads();
  if (tid < 64){
    int rr = blockIdx.x*64 + tid;
    float v[NCLS]; float m = -INFINITY;
    #pragma unroll
    for (int j = 0; j < NCLS; j++){
      v[j] = part[tid][0][j] + part[tid][1][j] + part[tid][2][j] + part[tid][3][j] + bias[j];
      m = fmaxf(m, v[j]);
    }
    float s = 0.f;
    #pragma unroll
    for (int j = 0; j < NCLS; j++) s += expf(v[j] - m);
    float ls = logf(s) + m;
    #pragma unroll
    for (int j = 0; j < NCLS; j++) out[(size_t)rr*NCLS + j] = v[j] - ls;
  }
}

// ---------------- host ----------------
extern "C" void kernel_launch(void* const* d_in, const int* in_sizes, int n_in,
                              void* d_out, int out_size, void* d_ws, size_t ws_size,
                              hipStream_t stream){
  const float* x    = (const float*)d_in[0];
  const int*   src  = (const int*)d_in[1];
  const int*   dst  = (const int*)d_in[2];
  const int*   batch= (const int*)d_in[3];
  const float* W0   = (const float*)d_in[4];
  const float* Wsm  = (const float*)d_in[5];
  const float* g_bn = (const float*)d_in[7];
  const float* b_bn = (const float*)d_in[8];
  const float* g_out= (const float*)d_in[9];
  const float* b_out= (const float*)d_in[10];
  const float* w1   = (const float*)d_in[11];
  const float* b1   = (const float*)d_in[12];
  const float* w2   = (const float*)d_in[13];
  const float* b2   = (const float*)d_in[14];
  const float* w3   = (const float*)d_in[15];
  const float* b3   = (const float*)d_in[16];

  int n = in_sizes[3];   // N_NODES
  int E = in_sizes[1];   // N_EDGES

  char* ws = (char*)d_ws;
  size_t off = 0;
  auto alloc = [&](size_t bytes) -> char* {
    char* p = ws + off;
    off += (bytes + 255) / 256 * 256;
    return p;
  };
  int*   degi      = (int*)  alloc((size_t)n*4);
  float* normv     = (float*)alloc((size_t)n*4);
  int*   row_start = (int*)  alloc((size_t)(n+1)*4);
  int*   cursor    = (int*)  alloc((size_t)n*4);
  int*   colA      = (int*)  alloc((size_t)E*4);
  int*   bsum      = (int*)  alloc(512*4);
  unsigned* U32    = (unsigned*)alloc((size_t)n*32*4);   // packed bf16, 128B/row
  size_t lstride   = ((size_t)n*64*4 + 255)/256*256/4;   // floats per layer buffer
  float* AGGall    = (float*)alloc((size_t)NLAYER*lstride*4);
  float* bnsums    = (float*)alloc(8*128*4);
  float* bnss      = (float*)alloc(NLAYER*128*4);        // per-layer [sc(64)|sh(64)]
  float* Hg        = (float*)alloc((size_t)NG*M3*4);
  float* Z1        = (float*)alloc((size_t)NG*M2*4);
  float* Z2        = (float*)alloc((size_t)NG*M1*4);
  float* zsc       = (float*)alloc(M3*4);
  float* zsh       = (float*)alloc(M3*4);

  int nb256 = (n + 255) / 256;
  int eb256 = (E + 255) / 256;

  hipMemsetAsync(degi, 0, (size_t)n*4, stream);
  k_deg<<<eb256, 256, 0, stream>>>(dst, E, degi);
  k_norm<<<nb256, 256, 0, stream>>>(degi, normv, n);
  k_scan_a<<<nb256, 256, 0, stream>>>(degi, n, row_start, bsum);
  k_scan_b<<<1, 512, 0, stream>>>(bsum, nb256);
  k_scan_c<<<nb256, 256, 0, stream>>>(row_start, bsum, cursor, n, E);
  { int chunks = 256; k_fill_x<<<NXCD*chunks, 256, 0, stream>>>(src, dst, E, n, cursor, colA, chunks); }

  float invn = 1.f / (float)n;
  for (int l = 0; l < NLAYER; l++){
    float* AGG = AGGall + (size_t)l*lstride;
    if (l == 0)
      k_node_gemm<128,0><<<nb256, 256, 0, stream>>>(x, 128, W0, normv, nullptr, U32, n);
    else
      k_node_gemm<64,1><<<nb256, 256, 0, stream>>>(AGGall + (size_t)(l-1)*lstride, 64,
                                                   Wsm + (size_t)(l-1)*64*64, normv,
                                                   bnss + (l-1)*128, U32, n);
    hipMemsetAsync(bnsums, 0, 8*128*4, stream);
    k_agg_bn<<<(n+31)/32, 256, 0, stream>>>(U32, row_start, colA, normv, AGG, bnsums, n);
    k_bn_finalize<<<1, 64, 0, stream>>>(bnsums, g_bn + l*64, b_bn + l*64, bnss + l*128, invn);
  }

  k_pool<<<NG, 256, 0, stream>>>(AGGall, lstride, bnss, batch, n, Hg);
  k_bn2<<<M3, 64, 0, stream>>>(Hg, g_out, b_out, zsc, zsh);

  { dim3 g1(M2/32, NG/32); k_gemm_t<<<g1, 256, 0, stream>>>(Hg, M3, w1, M2, b1, zsc, zsh, Z1, 1, 1); }
  { dim3 g2(M1/32, NG/32); k_gemm_t<<<g2, 256, 0, stream>>>(Z1, M2, w2, M1, b2, nullptr, nullptr, Z2, 1, 0); }
  k_gemm3_lsm<<<NG/64, 256, 0, stream>>>(Z2, w3, b3, (float*)d_out);
}

// Round 7
// 691.468 us; speedup vs baseline: 4.4087x; 1.0463x over previous
//
#include <hip/hip_runtime.h>
#include <hip/hip_bf16.h>
#include <math.h>

#define HIDC 64
#define NLAYER 4
#define NG 512
#define M3 768
#define M2 512
#define M1 256
#define NCLS 10
#define EPSV 1e-5f
#define NB 512          // partition buckets (dst >> 8), covers n < 131072
#define EPT 16          // edges per thread in scatter tile

// bf16 helpers (packed 2xbf16 in a uint32)
__device__ inline unsigned bf16rne(float x){
  unsigned u = __float_as_uint(x);
  return (u + 0x7fffu + ((u >> 16) & 1u)) >> 16;
}
__device__ inline unsigned packbf2(float lo, float hi){
  return bf16rne(lo) | (bf16rne(hi) << 16);
}
__device__ inline float blo(unsigned u){ return __uint_as_float(u << 16); }
__device__ inline float bhi(unsigned u){ return __uint_as_float(u & 0xffff0000u); }

// ---------------- graph build ----------------
__global__ void k_deg(const int* __restrict__ dst, int E, int* __restrict__ degi){
  int e = blockIdx.x*256 + threadIdx.x;
  if (e < E) atomicAdd(&degi[__builtin_nontemporal_load(&dst[e])], 1);
}

__global__ void k_norm(const int* __restrict__ degi, float* __restrict__ norm, int n){
  int i = blockIdx.x*256 + threadIdx.x;
  if (i < n){ float d = (float)(degi[i] + 1); norm[i] = rsqrtf(d); }
}

__global__ void k_scan_a(const int* __restrict__ degi, int n, int* __restrict__ row_start, int* __restrict__ bsum){
  __shared__ int tmp[256];
  int tid = threadIdx.x; int i = blockIdx.x*256 + tid;
  int v = (i < n) ? degi[i] : 0;
  tmp[tid] = v; __syncthreads();
  for (int ofs = 1; ofs < 256; ofs <<= 1){
    int t = (tid >= ofs) ? tmp[tid-ofs] : 0;
    __syncthreads();
    tmp[tid] += t;
    __syncthreads();
  }
  if (i < n) row_start[i] = tmp[tid] - v;   // block-local exclusive
  if (tid == 255) bsum[blockIdx.x] = tmp[255];
}

__global__ void k_scan_b(int* __restrict__ bsum, int nb){
  __shared__ int tmp[512];
  int tid = threadIdx.x;
  int v = (tid < nb) ? bsum[tid] : 0;
  tmp[tid] = v; __syncthreads();
  for (int ofs = 1; ofs < 512; ofs <<= 1){
    int t = (tid >= ofs) ? tmp[tid-ofs] : 0;
    __syncthreads();
    tmp[tid] += t;
    __syncthreads();
  }
  if (tid < nb) bsum[tid] = tmp[tid] - v;   // exclusive block offsets
}

__global__ void k_scan_c(int* __restrict__ row_start, const int* __restrict__ bsum,
                         int* __restrict__ cursor, int n, int E){
  int i = blockIdx.x*256 + threadIdx.x;
  if (i < n){
    int v = row_start[i] + bsum[blockIdx.x];
    row_start[i] = v;
    cursor[i] = v;
  }
  if (i == 0) row_start[n] = E;
}

// ---- bucket partition of the edge list by dst>>8 (write-locality by construction;
// r6 post-mortem: XCD-window + nt-loads did NOT stop write amplification) ----
__global__ __launch_bounds__(256) void k_bhist(const int* __restrict__ dst, int E,
                                               int* __restrict__ bcnt){
  __shared__ int lc[NB];
  int tid = threadIdx.x;
  for (int i = tid; i < NB; i += 256) lc[i] = 0;
  __syncthreads();
  for (int e = blockIdx.x*256 + tid; e < E; e += gridDim.x*256)
    atomicAdd(&lc[__builtin_nontemporal_load(&dst[e]) >> 8], 1);
  __syncthreads();
  for (int i = tid; i < NB; i += 256){
    int c = lc[i];
    if (c) atomicAdd(&bcnt[i], c);
  }
}

__global__ void k_bscan(const int* __restrict__ bcnt, int* __restrict__ bofs,
                        int* __restrict__ bcursor){
  __shared__ int tmp[NB];
  int tid = threadIdx.x;       // 512 threads
  int v = bcnt[tid];
  tmp[tid] = v; __syncthreads();
  for (int ofs = 1; ofs < NB; ofs <<= 1){
    int t = (tid >= ofs) ? tmp[tid-ofs] : 0;
    __syncthreads();
    tmp[tid] += t;
    __syncthreads();
  }
  int ex = tmp[tid] - v;
  bofs[tid] = ex;
  bcursor[tid] = ex;
}

// Each block: LDS histogram of its 4096-edge tile, ONE global atomic per
// (block,bucket) to reserve a contiguous sub-range, then append pairs.
// Every bucket's global write stream is sequential -> write amp ~1.
__global__ __launch_bounds__(256) void k_bscatter(const int* __restrict__ src,
    const int* __restrict__ dst, int E, int* __restrict__ bcursor, int2* __restrict__ stage){
  __shared__ int lcnt[NB];
  __shared__ int lbase[NB];
  int tid = threadIdx.x;
  int t0 = blockIdx.x*(256*EPT);
  for (int i = tid; i < NB; i += 256) lcnt[i] = 0;
  __syncthreads();
  int s_[EPT], d_[EPT];
  bool ok[EPT];
  #pragma unroll
  for (int i = 0; i < EPT; i++){
    int e = t0 + i*256 + tid;
    ok[i] = (e < E);
    int ee = ok[i] ? e : 0;
    d_[i] = __builtin_nontemporal_load(&dst[ee]);
    s_[i] = __builtin_nontemporal_load(&src[ee]);
    if (ok[i]) atomicAdd(&lcnt[d_[i] >> 8], 1);
  }
  __syncthreads();
  for (int i = tid; i < NB; i += 256){
    int c = lcnt[i];
    lbase[i] = c ? atomicAdd(&bcursor[i], c) : 0;
  }
  __syncthreads();
  #pragma unroll
  for (int i = 0; i < EPT; i++){
    if (ok[i]){
      int pos = atomicAdd(&lbase[d_[i] >> 8], 1);
      stage[pos] = make_int2(s_[i], d_[i]);
    }
  }
}

// One block per bucket: CSR fill confined to the bucket's ~16KB col region.
__global__ __launch_bounds__(256) void k_fill_b(const int2* __restrict__ stage,
    const int* __restrict__ bofs, const int* __restrict__ bcnt,
    int* __restrict__ cursor, int* __restrict__ col){
  int b = blockIdx.x;
  int st = bofs[b], en = st + bcnt[b];
  for (int i = st + threadIdx.x; i < en; i += 256){
    int2 p = stage[i];
    int pos = atomicAdd(&cursor[p.y], 1);
    col[pos] = p.x;
  }
}

// ---------------- node-level GEMM: U(bf16 packed) = ((A_bn) @ W) * norm[row] --------
template<int K, int BN>
__global__ __launch_bounds__(256) void k_node_gemm(const float* __restrict__ A, int lda,
      const float* __restrict__ W, const float* __restrict__ norm,
      const float* __restrict__ scsh, unsigned* __restrict__ U32, int n){
  __shared__ float4 Wl[K*16];   // K x 64 floats
  int tid = threadIdx.x;
  const float4* W4 = (const float4*)W;
  for (int idx = tid; idx < K*16; idx += 256) Wl[idx] = W4[idx];
  __syncthreads();
  int r = blockIdx.x*256 + tid;
  if (r >= n) return;
  float acc[64];
  #pragma unroll
  for (int c = 0; c < 64; c++) acc[c] = 0.f;
  const float* Ar = A + (size_t)r * lda;
  for (int k = 0; k < K; k += 4){
    float4 a4 = *(const float4*)(Ar + k);
    if (BN){
      a4.x = a4.x*scsh[k+0] + scsh[64+k+0];
      a4.y = a4.y*scsh[k+1] + scsh[64+k+1];
      a4.z = a4.z*scsh[k+2] + scsh[64+k+2];
      a4.w = a4.w*scsh[k+3] + scsh[64+k+3];
    }
    #pragma unroll
    for (int kk = 0; kk < 4; kk++){
      float a = (kk==0) ? a4.x : (kk==1) ? a4.y : (kk==2) ? a4.z : a4.w;
      #pragma unroll
      for (int c4 = 0; c4 < 16; c4++){
        float4 w = Wl[(k+kk)*16 + c4];
        acc[c4*4+0] += a * w.x;
        acc[c4*4+1] += a * w.y;
        acc[c4*4+2] += a * w.z;
        acc[c4*4+3] += a * w.w;
      }
    }
  }
  float nr = norm[r];
  uint4* Ur = (uint4*)(U32 + (size_t)r * 32);
  #pragma unroll
  for (int q = 0; q < 8; q++){
    uint4 o;
    o.x = packbf2(acc[q*8+0]*nr, acc[q*8+1]*nr);
    o.y = packbf2(acc[q*8+2]*nr, acc[q*8+3]*nr);
    o.z = packbf2(acc[q*8+4]*nr, acc[q*8+5]*nr);
    o.w = packbf2(acc[q*8+6]*nr, acc[q*8+7]*nr);
    Ur[q] = o;
  }
}

// ---------------- aggregation + fused BN stats (one node per wave) ----------------
__global__ __launch_bounds__(256) void k_agg_bn(const unsigned* __restrict__ U32,
    const int* __restrict__ row_start, const int* __restrict__ col,
    const float* __restrict__ norm, float* __restrict__ AGG,
    float* __restrict__ sums8, int n){
  int tid = threadIdx.x;
  int wv = tid >> 6;
  int lane = tid & 63;
  int half = lane >> 5;
  int cl = lane & 31;           // channel pair index: channels 2*cl, 2*cl+1
  float rs0=0.f, rs1=0.f, rq0=0.f, rq1=0.f;   // running stats (half 0 lanes)
  int base = blockIdx.x*32 + wv*8;
  for (int it = 0; it < 8; ++it){
    int node = __builtin_amdgcn_readfirstlane(base + it);
    if (node >= n) break;
    int st = row_start[node], en = row_start[node+1];
    float s0 = 0.f, s1 = 0.f;
    if (half == 0){               // self-loop term
      unsigned u = U32[(size_t)node*32 + cl];
      s0 = blo(u); s1 = bhi(u);
    }
    int k = st;
    for (; k + 16 <= en; k += 16){
      const int* cp = col + k + half*8;
      int j0 = cp[0], j1 = cp[1], j2 = cp[2], j3 = cp[3];
      int j4 = cp[4], j5 = cp[5], j6 = cp[6], j7 = cp[7];
      unsigned a = U32[(size_t)j0*32 + cl];
      unsigned b = U32[(size_t)j1*32 + cl];
      unsigned c = U32[(size_t)j2*32 + cl];
      unsigned d = U32[(size_t)j3*32 + cl];
      unsigned e = U32[(size_t)j4*32 + cl];
      unsigned f = U32[(size_t)j5*32 + cl];
      unsigned g = U32[(size_t)j6*32 + cl];
      unsigned h = U32[(size_t)j7*32 + cl];
      s0 += blo(a) + blo(b) + blo(c) + blo(d) + blo(e) + blo(f) + blo(g) + blo(h);
      s1 += bhi(a) + bhi(b) + bhi(c) + bhi(d) + bhi(e) + bhi(f) + bhi(g) + bhi(h);
    }
    for (int kk = k + half; kk < en; kk += 2){
      unsigned a = U32[(size_t)col[kk]*32 + cl];
      s0 += blo(a); s1 += bhi(a);
    }
    s0 += __shfl_xor(s0, 32);
    s1 += __shfl_xor(s1, 32);
    if (half == 0){
      float nr = norm[node];
      s0 *= nr; s1 *= nr;
      *(float2*)&AGG[(size_t)node*64 + 2*cl] = make_float2(s0, s1);
      rs0 += s0; rs1 += s1; rq0 += s0*s0; rq1 += s1*s1;
    }
  }
  __shared__ float L[4][32][4];
  if (half == 0){ L[wv][cl][0]=rs0; L[wv][cl][1]=rs1; L[wv][cl][2]=rq0; L[wv][cl][3]=rq1; }
  __syncthreads();
  if (tid < 128){
    int c2 = tid & 31, f = tid >> 5;   // f: 0=sum_lo 1=sum_hi 2=sq_lo 3=sq_hi
    float v = L[0][c2][f] + L[1][c2][f] + L[2][c2][f] + L[3][c2][f];
    int addr = ((f >= 2) ? 64 : 0) + 2*c2 + (f & 1);
    atomicAdd(&sums8[(blockIdx.x & 7)*128 + addr], v);
  }
}

// ---------------- batchnorm finalize: per-layer scale/shift ----------------
__global__ void k_bn_finalize(const float* __restrict__ sums8, const float* __restrict__ g,
                              const float* __restrict__ b, float* __restrict__ scsh, float invn){
  int c = threadIdx.x;
  float s1 = 0.f, s2 = 0.f;
  #pragma unroll
  for (int s = 0; s < 8; s++){ s1 += sums8[s*128 + c]; s2 += sums8[s*128 + 64 + c]; }
  float mean = s1*invn;
  float var = s2*invn - mean*mean;
  var = fmaxf(var, 0.f);
  float sv = g[c]*rsqrtf(var + EPSV);
  scsh[c] = sv;
  scsh[64 + c] = b[c] - mean*sv;
}

// ---------------- pooling, split 8x in the row dimension ----------------
__device__ inline int lowerb(const int* a, int n, int key){
  int lo = 0, hi = n;
  while (lo < hi){ int mid = (lo+hi) >> 1; if (a[mid] < key) lo = mid+1; else hi = mid; }
  return lo;
}

__global__ __launch_bounds__(256) void k_pool_part(const float* __restrict__ AGGall, size_t lstride,
    const float* __restrict__ bnss, const int* __restrict__ batch,
    int n, float* __restrict__ Ppart){
  int bid = blockIdx.x;
  int g = bid >> 3, sub = bid & 7;
  int c = threadIdx.x;
  int l = c >> 6, ch = c & 63;
  const float* A = AGGall + (size_t)l * lstride;
  float sc = bnss[l*128 + ch], sh = bnss[l*128 + 64 + ch];
  int st = lowerb(batch, n, g), en = lowerb(batch, n, g+1);
  int len = en - st;
  int r0 = st + (int)(((long long)sub * len) >> 3);
  int r1 = st + (int)(((long long)(sub+1) * len) >> 3);
  float s = 0.f, mx = -INFINITY;
  for (int r = r0; r < r1; r++){
    float v = A[(size_t)r*64 + ch]*sc + sh;
    s += v; mx = fmaxf(mx, v);
  }
  float* P = Ppart + (size_t)bid*512;
  P[c] = s;
  P[256 + c] = mx;
}

__global__ __launch_bounds__(256) void k_pool_comb(const float* __restrict__ Ppart,
    const int* __restrict__ batch, int n, float* __restrict__ Hg){
  int g = blockIdx.x; int c = threadIdx.x;
  float s = 0.f, mx = -INFINITY;
  #pragma unroll
  for (int sub = 0; sub < 8; sub++){
    const float* P = Ppart + (size_t)(g*8 + sub)*512;
    s += P[c];
    mx = fmaxf(mx, P[256 + c]);
  }
  int st = lowerb(batch, n, g), en = lowerb(batch, n, g+1);
  int cnt = en - st;
  float avg = s / (float)(cnt > 1 ? cnt : 1);
  float mo = (cnt > 0) ? mx : 0.f;
  Hg[(size_t)g*M3 + c]        = avg;
  Hg[(size_t)g*M3 + 256 + c]  = s;
  Hg[(size_t)g*M3 + 512 + c]  = mo;
}

// ---------------- readout BN (stats -> scale/shift) ----------------
__global__ void k_bn2(const float* __restrict__ Hg, const float* __restrict__ g,
                      const float* __restrict__ b, float* __restrict__ zsc, float* __restrict__ zsh){
  int c = blockIdx.x; int tid = threadIdx.x;  // 64 threads
  float s1 = 0.f, s2 = 0.f;
  for (int r = tid; r < NG; r += 64){
    float v = Hg[(size_t)r*M3 + c];
    s1 += v; s2 += v*v;
  }
  for (int o = 32; o > 0; o >>= 1){ s1 += __shfl_down(s1, o); s2 += __shfl_down(s2, o); }
  if (tid == 0){
    float mean = s1/(float)NG;
    float var = s2/(float)NG - mean*mean;
    var = fmaxf(var, 0.f);
    float sc = g[c]*rsqrtf(var + EPSV);
    zsc[c] = sc;
    zsh[c] = b[c] - mean*sc;
  }
}

// ---------------- tiled readout GEMM (32x32 tile, 2x2/thread) ----------------
__global__ __launch_bounds__(256) void k_gemm_t(const float* __restrict__ A, int K,
    const float* __restrict__ W, int N, const float* __restrict__ bias,
    const float* __restrict__ zsc, const float* __restrict__ zsh,
    float* __restrict__ out, int relu, int applybn){
  __shared__ float As[32][36];
  __shared__ float Bs[32][36];   // transposed: Bs[n][k]
  int tid = threadIdx.x;
  int tx = tid & 15, ty = tid >> 4;
  int rb = blockIdx.y << 5, cb = blockIdx.x << 5;
  int lr = tid >> 3;            // 0..31
  int lk = (tid & 7) << 2;      // 0,4,...,28
  float acc00=0.f, acc01=0.f, acc10=0.f, acc11=0.f;
  for (int k0 = 0; k0 < K; k0 += 32){
    float4 av = *(const float4*)&A[(size_t)(rb+lr)*K + k0 + lk];
    if (applybn){
      av.x = av.x*zsc[k0+lk+0] + zsh[k0+lk+0];
      av.y = av.y*zsc[k0+lk+1] + zsh[k0+lk+1];
      av.z = av.z*zsc[k0+lk+2] + zsh[k0+lk+2];
      av.w = av.w*zsc[k0+lk+3] + zsh[k0+lk+3];
    }
    *(float4*)&As[lr][lk] = av;
    float4 bv = *(const float4*)&W[(size_t)(k0+lr)*N + cb + lk];
    Bs[lk+0][lr] = bv.x;
    Bs[lk+1][lr] = bv.y;
    Bs[lk+2][lr] = bv.z;
    Bs[lk+3][lr] = bv.w;
    __syncthreads();
    #pragma unroll
    for (int kk = 0; kk < 32; kk += 4){
      float4 a0 = *(const float4*)&As[ty][kk];
      float4 a1 = *(const float4*)&As[ty+16][kk];
      float4 b0 = *(const float4*)&Bs[tx][kk];
      float4 b1 = *(const float4*)&Bs[tx+16][kk];
      acc00 += a0.x*b0.x + a0.y*b0.y + a0.z*b0.z + a0.w*b0.w;
      acc01 += a0.x*b1.x + a0.y*b1.y + a0.z*b1.z + a0.w*b1.w;
      acc10 += a1.x*b0.x + a1.y*b0.y + a1.z*b0.z + a1.w*b0.w;
      acc11 += a1.x*b1.x + a1.y*b1.y + a1.z*b1.z + a1.w*b1.w;
    }
    __syncthreads();
  }
  int c0 = cb + tx, c1 = cb + tx + 16;
  float bz0 = bias[c0], bz1 = bias[c1];
  acc00 += bz0; acc01 += bz1; acc10 += bz0; acc11 += bz1;
  if (relu){
    acc00 = fmaxf(acc00, 0.f); acc01 = fmaxf(acc01, 0.f);
    acc10 = fmaxf(acc10, 0.f); acc11 = fmaxf(acc11, 0.f);
  }
  out[(size_t)(rb+ty)*N + c0]      = acc00;
  out[(size_t)(rb+ty)*N + c1]      = acc01;
  out[(size_t)(rb+ty+16)*N + c0]   = acc10;
  out[(size_t)(rb+ty+16)*N + c1]   = acc11;
}

// ---------------- final tiny GEMM (K=256, N=10) fused with log-softmax --------
__global__ __launch_bounds__(256) void k_gemm3_lsm(const float* __restrict__ A,
    const float* __restrict__ W, const float* __restrict__ bias, float* __restrict__ out){
  __shared__ float Wl[M1*NCLS];       // 10 KB
  __shared__ float part[64][4][NCLS]; // 10 KB
  int tid = threadIdx.x;
  for (int i = tid; i < M1*NCLS; i += 256) Wl[i] = W[i];
  __syncthreads();
  int r = blockIdx.x*64 + (tid >> 2);
  int q = tid & 3;
  float acc[NCLS];
  #pragma unroll
  for (int j = 0; j < NCLS; j++) acc[j] = 0.f;
  const float4* A4 = (const float4*)(A + (size_t)r*M1 + q*64);
  for (int kq = 0; kq < 16; kq++){
    float4 a = A4[kq];
    int kb = q*64 + kq*4;
    #pragma unroll
    for (int j = 0; j < NCLS; j++){
      acc[j] += a.x*Wl[(kb+0)*NCLS+j] + a.y*Wl[(kb+1)*NCLS+j]
              + a.z*Wl[(kb+2)*NCLS+j] + a.w*Wl[(kb+3)*NCLS+j];
    }
  }
  #pragma unroll
  for (int j = 0; j < NCLS; j++) part[tid>>2][q][j] = acc[j];
  __syncthreads();
  if (tid < 64){
    int rr = blockIdx.x*64 + tid;
    float v[NCLS]; float m = -INFINITY;
    #pragma unroll
    for (int j = 0; j < NCLS; j++){
      v[j] = part[tid][0][j] + part[tid][1][j] + part[tid][2][j] + part[tid][3][j] + bias[j];
      m = fmaxf(m, v[j]);
    }
    float s = 0.f;
    #pragma unroll
    for (int j = 0; j < NCLS; j++) s += expf(v[j] - m);
    float ls = logf(s) + m;
    #pragma unroll
    for (int j = 0; j < NCLS; j++) out[(size_t)rr*NCLS + j] = v[j] - ls;
  }
}

// ---------------- host ----------------
extern "C" void kernel_launch(void* const* d_in, const int* in_sizes, int n_in,
                              void* d_out, int out_size, void* d_ws, size_t ws_size,
                              hipStream_t stream){
  const float* x    = (const float*)d_in[0];
  const int*   src  = (const int*)d_in[1];
  const int*   dst  = (const int*)d_in[2];
  const int*   batch= (const int*)d_in[3];
  const float* W0   = (const float*)d_in[4];
  const float* Wsm  = (const float*)d_in[5];
  const float* g_bn = (const float*)d_in[7];
  const float* b_bn = (const float*)d_in[8];
  const float* g_out= (const float*)d_in[9];
  const float* b_out= (const float*)d_in[10];
  const float* w1   = (const float*)d_in[11];
  const float* b1   = (const float*)d_in[12];
  const float* w2   = (const float*)d_in[13];
  const float* b2   = (const float*)d_in[14];
  const float* w3   = (const float*)d_in[15];
  const float* b3   = (const float*)d_in[16];

  int n = in_sizes[3];   // N_NODES
  int E = in_sizes[1];   // N_EDGES

  char* ws = (char*)d_ws;
  size_t off = 0;
  auto alloc = [&](size_t bytes) -> char* {
    char* p = ws + off;
    off += (bytes + 255) / 256 * 256;
    return p;
  };
  int*   degi      = (int*)  alloc((size_t)n*4);
  float* normv     = (float*)alloc((size_t)n*4);
  int*   row_start = (int*)  alloc((size_t)(n+1)*4);
  int*   cursor    = (int*)  alloc((size_t)n*4);
  int*   colA      = (int*)  alloc((size_t)E*4);
  int*   bsum      = (int*)  alloc(512*4);
  int*   bcnt      = (int*)  alloc(NB*4);
  int*   bofs      = (int*)  alloc(NB*4);
  int*   bcursor   = (int*)  alloc(NB*4);
  int2*  stage     = (int2*) alloc((size_t)E*8);
  unsigned* U32    = (unsigned*)alloc((size_t)n*32*4);   // packed bf16, 128B/row
  size_t lstride   = ((size_t)n*64*4 + 255)/256*256/4;   // floats per layer buffer
  float* AGGall    = (float*)alloc((size_t)NLAYER*lstride*4);
  float* bnsums    = (float*)alloc(8*128*4);
  float* bnss      = (float*)alloc(NLAYER*128*4);        // per-layer [sc(64)|sh(64)]
  float* Ppart     = (float*)alloc((size_t)NG*8*512*4);
  float* Hg        = (float*)alloc((size_t)NG*M3*4);
  float* Z1        = (float*)alloc((size_t)NG*M2*4);
  float* Z2        = (float*)alloc((size_t)NG*M1*4);
  float* zsc       = (float*)alloc(M3*4);
  float* zsh       = (float*)alloc(M3*4);

  int nb256 = (n + 255) / 256;
  int eb256 = (E + 255) / 256;
  int nb_used = (n + 255) >> 8;          // buckets actually populated

  hipMemsetAsync(degi, 0, (size_t)n*4, stream);
  hipMemsetAsync(bcnt, 0, NB*4, stream);
  k_deg<<<eb256, 256, 0, stream>>>(dst, E, degi);
  k_norm<<<nb256, 256, 0, stream>>>(degi, normv, n);
  k_scan_a<<<nb256, 256, 0, stream>>>(degi, n, row_start, bsum);
  k_scan_b<<<1, 512, 0, stream>>>(bsum, nb256);
  k_scan_c<<<nb256, 256, 0, stream>>>(row_start, bsum, cursor, n, E);
  k_bhist<<<512, 256, 0, stream>>>(dst, E, bcnt);
  k_bscan<<<1, NB, 0, stream>>>(bcnt, bofs, bcursor);
  { int tiles = (E + 256*EPT - 1)/(256*EPT);
    k_bscatter<<<tiles, 256, 0, stream>>>(src, dst, E, bcursor, stage); }
  k_fill_b<<<nb_used, 256, 0, stream>>>(stage, bofs, bcnt, cursor, colA);

  float invn = 1.f / (float)n;
  for (int l = 0; l < NLAYER; l++){
    float* AGG = AGGall + (size_t)l*lstride;
    if (l == 0)
      k_node_gemm<128,0><<<nb256, 256, 0, stream>>>(x, 128, W0, normv, nullptr, U32, n);
    else
      k_node_gemm<64,1><<<nb256, 256, 0, stream>>>(AGGall + (size_t)(l-1)*lstride, 64,
                                                   Wsm + (size_t)(l-1)*64*64, normv,
                                                   bnss + (l-1)*128, U32, n);
    hipMemsetAsync(bnsums, 0, 8*128*4, stream);
    k_agg_bn<<<(n+31)/32, 256, 0, stream>>>(U32, row_start, colA, normv, AGG, bnsums, n);
    k_bn_finalize<<<1, 64, 0, stream>>>(bnsums, g_bn + l*64, b_bn + l*64, bnss + l*128, invn);
  }

  k_pool_part<<<NG*8, 256, 0, stream>>>(AGGall, lstride, bnss, batch, n, Ppart);
  k_pool_comb<<<NG, 256, 0, stream>>>(Ppart, batch, n, Hg);
  k_bn2<<<M3, 64, 0, stream>>>(Hg, g_out, b_out, zsc, zsh);

  { dim3 g1(M2/32, NG/32); k_gemm_t<<<g1, 256, 0, stream>>>(Hg, M3, w1, M2, b1, zsc, zsh, Z1, 1, 1); }
  { dim3 g2(M1/32, NG/32); k_gemm_t<<<g2, 256, 0, stream>>>(Z1, M2, w2, M1, b2, nullptr, nullptr, Z2, 1, 0); }
  k_gemm3_lsm<<<NG/64, 256, 0, stream>>>(Z2, w3, b3, (float*)d_out);
}

// Round 8
// 569.708 us; speedup vs baseline: 5.3510x; 1.2137x over previous
//
#include <hip/hip_runtime.h>
#include <hip/hip_bf16.h>
#include <math.h>

#define HIDC 64
#define NLAYER 4
#define NG 512
#define M3 768
#define M2 512
#define M1 256
#define NCLS 10
#define EPSV 1e-5f
#define NB 512          // partition buckets (dst >> 8), covers n < 131072
#define EPT 16          // edges per thread in scatter tile
#define NPW 4           // nodes per wave in aggregation

// bf16 helpers (packed 2xbf16 in a uint32)
__device__ inline unsigned bf16rne(float x){
  unsigned u = __float_as_uint(x);
  return (u + 0x7fffu + ((u >> 16) & 1u)) >> 16;
}
__device__ inline unsigned packbf2(float lo, float hi){
  return bf16rne(lo) | (bf16rne(hi) << 16);
}
__device__ inline float blo(unsigned u){ return __uint_as_float(u << 16); }
__device__ inline float bhi(unsigned u){ return __uint_as_float(u & 0xffff0000u); }

// ---------------- graph build ----------------
__global__ void k_deg(const int* __restrict__ dst, int E, int* __restrict__ degi){
  int e = blockIdx.x*256 + threadIdx.x;
  if (e < E) atomicAdd(&degi[__builtin_nontemporal_load(&dst[e])], 1);
}

__global__ void k_norm(const int* __restrict__ degi, float* __restrict__ norm, int n){
  int i = blockIdx.x*256 + threadIdx.x;
  if (i < n){ float d = (float)(degi[i] + 1); norm[i] = rsqrtf(d); }
}

__global__ void k_scan_a(const int* __restrict__ degi, int n, int* __restrict__ row_start, int* __restrict__ bsum){
  __shared__ int tmp[256];
  int tid = threadIdx.x; int i = blockIdx.x*256 + tid;
  int v = (i < n) ? degi[i] : 0;
  tmp[tid] = v; __syncthreads();
  for (int ofs = 1; ofs < 256; ofs <<= 1){
    int t = (tid >= ofs) ? tmp[tid-ofs] : 0;
    __syncthreads();
    tmp[tid] += t;
    __syncthreads();
  }
  if (i < n) row_start[i] = tmp[tid] - v;   // block-local exclusive
  if (tid == 255) bsum[blockIdx.x] = tmp[255];
}

__global__ void k_scan_b(int* __restrict__ bsum, int nb){
  __shared__ int tmp[512];
  int tid = threadIdx.x;
  int v = (tid < nb) ? bsum[tid] : 0;
  tmp[tid] = v; __syncthreads();
  for (int ofs = 1; ofs < 512; ofs <<= 1){
    int t = (tid >= ofs) ? tmp[tid-ofs] : 0;
    __syncthreads();
    tmp[tid] += t;
    __syncthreads();
  }
  if (tid < nb) bsum[tid] = tmp[tid] - v;   // exclusive block offsets
}

__global__ void k_scan_c(int* __restrict__ row_start, const int* __restrict__ bsum,
                         int* __restrict__ cursor, int n, int E){
  int i = blockIdx.x*256 + threadIdx.x;
  if (i < n){
    int v = row_start[i] + bsum[blockIdx.x];
    row_start[i] = v;
    cursor[i] = v;
  }
  if (i == 0) row_start[n] = E;
}

// bucket counts = 256-wide sums of degi (replaces re-scanning dst)
__global__ void k_bcnt_from_deg(const int* __restrict__ degi, int n, int* __restrict__ bcnt){
  __shared__ int l[256];
  int i = blockIdx.x*256 + threadIdx.x;
  l[threadIdx.x] = (i < n) ? degi[i] : 0;
  __syncthreads();
  for (int o = 128; o > 0; o >>= 1){
    if (threadIdx.x < o) l[threadIdx.x] += l[threadIdx.x + o];
    __syncthreads();
  }
  if (threadIdx.x == 0) bcnt[blockIdx.x] = l[0];
}

__global__ void k_bscan(const int* __restrict__ bcnt, int* __restrict__ bofs,
                        int* __restrict__ bcursor){
  __shared__ int tmp[NB];
  int tid = threadIdx.x;       // 512 threads
  int v = bcnt[tid];
  tmp[tid] = v; __syncthreads();
  for (int ofs = 1; ofs < NB; ofs <<= 1){
    int t = (tid >= ofs) ? tmp[tid-ofs] : 0;
    __syncthreads();
    tmp[tid] += t;
    __syncthreads();
  }
  int ex = tmp[tid] - v;
  bofs[tid] = ex;
  bcursor[tid] = ex;
}

// Each block: LDS histogram of its 4096-edge tile, ONE global atomic per
// (block,bucket) to reserve a contiguous sub-range, then append pairs.
__global__ __launch_bounds__(256) void k_bscatter(const int* __restrict__ src,
    const int* __restrict__ dst, int E, int* __restrict__ bcursor, int2* __restrict__ stage){
  __shared__ int lcnt[NB];
  __shared__ int lbase[NB];
  int tid = threadIdx.x;
  int t0 = blockIdx.x*(256*EPT);
  for (int i = tid; i < NB; i += 256) lcnt[i] = 0;
  __syncthreads();
  int s_[EPT], d_[EPT];
  bool ok[EPT];
  #pragma unroll
  for (int i = 0; i < EPT; i++){
    int e = t0 + i*256 + tid;
    ok[i] = (e < E);
    int ee = ok[i] ? e : 0;
    d_[i] = __builtin_nontemporal_load(&dst[ee]);
    s_[i] = __builtin_nontemporal_load(&src[ee]);
    if (ok[i]) atomicAdd(&lcnt[d_[i] >> 8], 1);
  }
  __syncthreads();
  for (int i = tid; i < NB; i += 256){
    int c = lcnt[i];
    lbase[i] = c ? atomicAdd(&bcursor[i], c) : 0;
  }
  __syncthreads();
  #pragma unroll
  for (int i = 0; i < EPT; i++){
    if (ok[i]){
      int pos = atomicAdd(&lbase[d_[i] >> 8], 1);
      stage[pos] = make_int2(s_[i], d_[i]);
    }
  }
}

// One block per bucket: CSR fill confined to the bucket's ~16KB col region.
__global__ __launch_bounds__(256) void k_fill_b(const int2* __restrict__ stage,
    const int* __restrict__ bofs, const int* __restrict__ bcnt,
    int* __restrict__ cursor, int* __restrict__ col){
  int b = blockIdx.x;
  int st = bofs[b], en = st + bcnt[b];
  for (int i = st + threadIdx.x; i < en; i += 256){
    int2 p = stage[i];
    int pos = atomicAdd(&cursor[p.y], 1);
    col[pos] = p.x;
  }
}

// ---------------- node GEMM layer 0: U(bf16) = (x @ W0) * norm[row] ----------------
template<int K>
__global__ __launch_bounds__(256) void k_node_gemm(const float* __restrict__ A, int lda,
      const float* __restrict__ W, const float* __restrict__ norm, unsigned* __restrict__ U32, int n){
  __shared__ float4 Wl[K*16];   // K x 64 floats
  int tid = threadIdx.x;
  const float4* W4 = (const float4*)W;
  for (int idx = tid; idx < K*16; idx += 256) Wl[idx] = W4[idx];
  __syncthreads();
  int r = blockIdx.x*256 + tid;
  if (r >= n) return;
  float acc[64];
  #pragma unroll
  for (int c = 0; c < 64; c++) acc[c] = 0.f;
  const float* Ar = A + (size_t)r * lda;
  for (int k = 0; k < K; k += 4){
    float4 a4 = *(const float4*)(Ar + k);
    #pragma unroll
    for (int kk = 0; kk < 4; kk++){
      float a = (kk==0) ? a4.x : (kk==1) ? a4.y : (kk==2) ? a4.z : a4.w;
      #pragma unroll
      for (int c4 = 0; c4 < 16; c4++){
        float4 w = Wl[(k+kk)*16 + c4];
        acc[c4*4+0] += a * w.x;
        acc[c4*4+1] += a * w.y;
        acc[c4*4+2] += a * w.z;
        acc[c4*4+3] += a * w.w;
      }
    }
  }
  float nr = norm[r];
  uint4* Ur = (uint4*)(U32 + (size_t)r * 32);
  #pragma unroll
  for (int q = 0; q < 8; q++){
    uint4 o;
    o.x = packbf2(acc[q*8+0]*nr, acc[q*8+1]*nr);
    o.y = packbf2(acc[q*8+2]*nr, acc[q*8+3]*nr);
    o.z = packbf2(acc[q*8+4]*nr, acc[q*8+5]*nr);
    o.w = packbf2(acc[q*8+6]*nr, acc[q*8+7]*nr);
    Ur[q] = o;
  }
}

// ---------------- node GEMM layers 1+: A is bf16-packed AGG, BN applied on load ----
__global__ __launch_bounds__(256) void k_node_gemm_b(const unsigned* __restrict__ Ab,
      const float* __restrict__ W, const float* __restrict__ norm,
      const float* __restrict__ scsh, unsigned* __restrict__ U32, int n){
  __shared__ float4 Wl[64*16];
  __shared__ float ss[128];
  int tid = threadIdx.x;
  const float4* W4 = (const float4*)W;
  for (int idx = tid; idx < 64*16; idx += 256) Wl[idx] = W4[idx];
  if (tid < 128) ss[tid] = scsh[tid];
  __syncthreads();
  int r = blockIdx.x*256 + tid;
  if (r >= n) return;
  float acc[64];
  #pragma unroll
  for (int c = 0; c < 64; c++) acc[c] = 0.f;
  const uint4* Ar = (const uint4*)(Ab + (size_t)r*32);
  for (int q = 0; q < 8; q++){
    uint4 u = Ar[q];
    float a[8];
    a[0]=blo(u.x); a[1]=bhi(u.x); a[2]=blo(u.y); a[3]=bhi(u.y);
    a[4]=blo(u.z); a[5]=bhi(u.z); a[6]=blo(u.w); a[7]=bhi(u.w);
    #pragma unroll
    for (int kk = 0; kk < 8; kk++){
      int k = q*8 + kk;
      float av = a[kk]*ss[k] + ss[64+k];
      #pragma unroll
      for (int c4 = 0; c4 < 16; c4++){
        float4 w = Wl[k*16 + c4];
        acc[c4*4+0] += av * w.x;
        acc[c4*4+1] += av * w.y;
        acc[c4*4+2] += av * w.z;
        acc[c4*4+3] += av * w.w;
      }
    }
  }
  float nr = norm[r];
  uint4* Ur = (uint4*)(U32 + (size_t)r * 32);
  #pragma unroll
  for (int q = 0; q < 8; q++){
    uint4 o;
    o.x = packbf2(acc[q*8+0]*nr, acc[q*8+1]*nr);
    o.y = packbf2(acc[q*8+2]*nr, acc[q*8+3]*nr);
    o.z = packbf2(acc[q*8+4]*nr, acc[q*8+5]*nr);
    o.w = packbf2(acc[q*8+6]*nr, acc[q*8+7]*nr);
    Ur[q] = o;
  }
}

// ---------------- aggregation + fused BN stats ----------------
// One node per wave (wave-uniform bounds), NPW nodes sequentially per wave.
// Two 32-lane halves handle different edges (U row = 128B = 32 lanes x 4B).
// All iterations are full-width 16-edge masked iterations: invalid lanes
// re-read col[st] (always valid) and their contribution is zeroed via FMA
// mask -- no serial tail (r7 post-mortem: 2-edge serial tail dominated).
// Output AGG is bf16-packed (BN stats still fp32 from registers).
__global__ __launch_bounds__(256) void k_agg_bn(const unsigned* __restrict__ U32,
    const int* __restrict__ row_start, const int* __restrict__ col,
    const float* __restrict__ norm, unsigned* __restrict__ AGGb,
    float* __restrict__ sums8, int n){
  int tid = threadIdx.x;
  int wv = tid >> 6;
  int lane = tid & 63;
  int half = lane >> 5;
  int cl = lane & 31;           // channel pair index: channels 2*cl, 2*cl+1
  float rs0=0.f, rs1=0.f, rq0=0.f, rq1=0.f;   // running stats (half 0 lanes)
  int base = blockIdx.x*(4*NPW) + wv*NPW;
  #pragma unroll
  for (int it = 0; it < NPW; ++it){
    int node = __builtin_amdgcn_readfirstlane(base + it);
    bool nv = (node < n);
    int nodec = nv ? node : 0;
    int st = row_start[nodec], en = row_start[nodec+1];
    float s0 = 0.f, s1 = 0.f;
    if (half == 0){               // self-loop term
      unsigned u = U32[(size_t)nodec*32 + cl];
      s0 = blo(u); s1 = bhi(u);
    }
    int nit = (en - st + 15) >> 4;
    for (int i = 0; i < nit; i++){
      int k = st + i*16 + half*8;
      unsigned ua[8]; float m[8];
      #pragma unroll
      for (int j = 0; j < 8; j++){
        int kk = k + j;
        bool v = (kk < en);
        int idx = v ? kk : st;
        int jn = col[idx];
        ua[j] = U32[(size_t)jn*32 + cl];
        m[j] = v ? 1.f : 0.f;
      }
      #pragma unroll
      for (int j = 0; j < 8; j++){
        s0 += m[j]*blo(ua[j]);
        s1 += m[j]*bhi(ua[j]);
      }
    }
    s0 += __shfl_xor(s0, 32);
    s1 += __shfl_xor(s1, 32);
    if (half == 0 && nv){
      float nr = norm[node];
      s0 *= nr; s1 *= nr;
      AGGb[(size_t)node*32 + cl] = packbf2(s0, s1);
      rs0 += s0; rs1 += s1; rq0 += s0*s0; rq1 += s1*s1;
    }
  }
  __shared__ float L[4][32][4];
  if (half == 0){ L[wv][cl][0]=rs0; L[wv][cl][1]=rs1; L[wv][cl][2]=rq0; L[wv][cl][3]=rq1; }
  __syncthreads();
  if (tid < 128){
    int c2 = tid & 31, f = tid >> 5;   // f: 0=sum_lo 1=sum_hi 2=sq_lo 3=sq_hi
    float v = L[0][c2][f] + L[1][c2][f] + L[2][c2][f] + L[3][c2][f];
    int addr = ((f >= 2) ? 64 : 0) + 2*c2 + (f & 1);
    atomicAdd(&sums8[(blockIdx.x & 7)*128 + addr], v);
  }
}

// ---------------- batchnorm finalize: per-layer scale/shift ----------------
__global__ void k_bn_finalize(const float* __restrict__ sums8, const float* __restrict__ g,
                              const float* __restrict__ b, float* __restrict__ scsh, float invn){
  int c = threadIdx.x;
  float s1 = 0.f, s2 = 0.f;
  #pragma unroll
  for (int s = 0; s < 8; s++){ s1 += sums8[s*128 + c]; s2 += sums8[s*128 + 64 + c]; }
  float mean = s1*invn;
  float var = s2*invn - mean*mean;
  var = fmaxf(var, 0.f);
  float sv = g[c]*rsqrtf(var + EPSV);
  scsh[c] = sv;
  scsh[64 + c] = b[c] - mean*sv;
}

// ---------------- pooling, split 8x in the row dimension (bf16 AGG input) -------
__device__ inline int lowerb(const int* a, int n, int key){
  int lo = 0, hi = n;
  while (lo < hi){ int mid = (lo+hi) >> 1; if (a[mid] < key) lo = mid+1; else hi = mid; }
  return lo;
}

__global__ __launch_bounds__(256) void k_pool_part(const unsigned* __restrict__ AGGall,
    size_t lstride32, const float* __restrict__ bnss, const int* __restrict__ batch,
    int n, float* __restrict__ Ppart){
  int bid = blockIdx.x;
  int g = bid >> 3, sub = bid & 7;
  int c = threadIdx.x;
  int l = c >> 6, ch = c & 63;
  const unsigned* A = AGGall + (size_t)l * lstride32;
  float sc = bnss[l*128 + ch], sh = bnss[l*128 + 64 + ch];
  int hi16 = ch & 1;
  int uofs = ch >> 1;
  int st = lowerb(batch, n, g), en = lowerb(batch, n, g+1);
  int len = en - st;
  int r0 = st + (int)(((long long)sub * len) >> 3);
  int r1 = st + (int)(((long long)(sub+1) * len) >> 3);
  float s = 0.f, mx = -INFINITY;
  for (int r = r0; r < r1; r++){
    unsigned u = A[(size_t)r*32 + uofs];
    float v = hi16 ? bhi(u) : blo(u);
    v = v*sc + sh;
    s += v; mx = fmaxf(mx, v);
  }
  float* P = Ppart + (size_t)bid*512;
  P[c] = s;
  P[256 + c] = mx;
}

__global__ __launch_bounds__(256) void k_pool_comb(const float* __restrict__ Ppart,
    const int* __restrict__ batch, int n, float* __restrict__ Hg){
  int g = blockIdx.x; int c = threadIdx.x;
  float s = 0.f, mx = -INFINITY;
  #pragma unroll
  for (int sub = 0; sub < 8; sub++){
    const float* P = Ppart + (size_t)(g*8 + sub)*512;
    s += P[c];
    mx = fmaxf(mx, P[256 + c]);
  }
  int st = lowerb(batch, n, g), en = lowerb(batch, n, g+1);
  int cnt = en - st;
  float avg = s / (float)(cnt > 1 ? cnt : 1);
  float mo = (cnt > 0) ? mx : 0.f;
  Hg[(size_t)g*M3 + c]        = avg;
  Hg[(size_t)g*M3 + 256 + c]  = s;
  Hg[(size_t)g*M3 + 512 + c]  = mo;
}

// ---------------- readout BN (stats -> scale/shift) ----------------
__global__ void k_bn2(const float* __restrict__ Hg, const float* __restrict__ g,
                      const float* __restrict__ b, float* __restrict__ zsc, float* __restrict__ zsh){
  int c = blockIdx.x; int tid = threadIdx.x;  // 64 threads
  float s1 = 0.f, s2 = 0.f;
  for (int r = tid; r < NG; r += 64){
    float v = Hg[(size_t)r*M3 + c];
    s1 += v; s2 += v*v;
  }
  for (int o = 32; o > 0; o >>= 1){ s1 += __shfl_down(s1, o); s2 += __shfl_down(s2, o); }
  if (tid == 0){
    float mean = s1/(float)NG;
    float var = s2/(float)NG - mean*mean;
    var = fmaxf(var, 0.f);
    float sc = g[c]*rsqrtf(var + EPSV);
    zsc[c] = sc;
    zsh[c] = b[c] - mean*sc;
  }
}

// ---------------- tiled readout GEMM (32x32 tile, 2x2/thread) ----------------
__global__ __launch_bounds__(256) void k_gemm_t(const float* __restrict__ A, int K,
    const float* __restrict__ W, int N, const float* __restrict__ bias,
    const float* __restrict__ zsc, const float* __restrict__ zsh,
    float* __restrict__ out, int relu, int applybn){
  __shared__ float As[32][36];
  __shared__ float Bs[32][36];   // transposed: Bs[n][k]
  int tid = threadIdx.x;
  int tx = tid & 15, ty = tid >> 4;
  int rb = blockIdx.y << 5, cb = blockIdx.x << 5;
  int lr = tid >> 3;            // 0..31
  int lk = (tid & 7) << 2;      // 0,4,...,28
  float acc00=0.f, acc01=0.f, acc10=0.f, acc11=0.f;
  for (int k0 = 0; k0 < K; k0 += 32){
    float4 av = *(const float4*)&A[(size_t)(rb+lr)*K + k0 + lk];
    if (applybn){
      av.x = av.x*zsc[k0+lk+0] + zsh[k0+lk+0];
      av.y = av.y*zsc[k0+lk+1] + zsh[k0+lk+1];
      av.z = av.z*zsc[k0+lk+2] + zsh[k0+lk+2];
      av.w = av.w*zsc[k0+lk+3] + zsh[k0+lk+3];
    }
    *(float4*)&As[lr][lk] = av;
    float4 bv = *(const float4*)&W[(size_t)(k0+lr)*N + cb + lk];
    Bs[lk+0][lr] = bv.x;
    Bs[lk+1][lr] = bv.y;
    Bs[lk+2][lr] = bv.z;
    Bs[lk+3][lr] = bv.w;
    __syncthreads();
    #pragma unroll
    for (int kk = 0; kk < 32; kk += 4){
      float4 a0 = *(const float4*)&As[ty][kk];
      float4 a1 = *(const float4*)&As[ty+16][kk];
      float4 b0 = *(const float4*)&Bs[tx][kk];
      float4 b1 = *(const float4*)&Bs[tx+16][kk];
      acc00 += a0.x*b0.x + a0.y*b0.y + a0.z*b0.z + a0.w*b0.w;
      acc01 += a0.x*b1.x + a0.y*b1.y + a0.z*b1.z + a0.w*b1.w;
      acc10 += a1.x*b0.x + a1.y*b0.y + a1.z*b0.z + a1.w*b0.w;
      acc11 += a1.x*b1.x + a1.y*b1.y + a1.z*b1.z + a1.w*b1.w;
    }
    __syncthreads();
  }
  int c0 = cb + tx, c1 = cb + tx + 16;
  float bz0 = bias[c0], bz1 = bias[c1];
  acc00 += bz0; acc01 += bz1; acc10 += bz0; acc11 += bz1;
  if (relu){
    acc00 = fmaxf(acc00, 0.f); acc01 = fmaxf(acc01, 0.f);
    acc10 = fmaxf(acc10, 0.f); acc11 = fmaxf(acc11, 0.f);
  }
  out[(size_t)(rb+ty)*N + c0]      = acc00;
  out[(size_t)(rb+ty)*N + c1]      = acc01;
  out[(size_t)(rb+ty+16)*N + c0]   = acc10;
  out[(size_t)(rb+ty+16)*N + c1]   = acc11;
}

// ---------------- final tiny GEMM (K=256, N=10) fused with log-softmax --------
__global__ __launch_bounds__(256) void k_gemm3_lsm(const float* __restrict__ A,
    const float* __restrict__ W, const float* __restrict__ bias, float* __restrict__ out){
  __shared__ float Wl[M1*NCLS];       // 10 KB
  __shared__ float part[64][4][NCLS]; // 10 KB
  int tid = threadIdx.x;
  for (int i = tid; i < M1*NCLS; i += 256) Wl[i] = W[i];
  __syncthreads();
  int r = blockIdx.x*64 + (tid >> 2);
  int q = tid & 3;
  float acc[NCLS];
  #pragma unroll
  for (int j = 0; j < NCLS; j++) acc[j] = 0.f;
  const float4* A4 = (const float4*)(A + (size_t)r*M1 + q*64);
  for (int kq = 0; kq < 16; kq++){
    float4 a = A4[kq];
    int kb = q*64 + kq*4;
    #pragma unroll
    for (int j = 0; j < NCLS; j++){
      acc[j] += a.x*Wl[(kb+0)*NCLS+j] + a.y*Wl[(kb+1)*NCLS+j]
              + a.z*Wl[(kb+2)*NCLS+j] + a.w*Wl[(kb+3)*NCLS+j];
    }
  }
  #pragma unroll
  for (int j = 0; j < NCLS; j++) part[tid>>2][q][j] = acc[j];
  __syncthreads();
  if (tid < 64){
    int rr = blockIdx.x*64 + tid;
    float v[NCLS]; float m = -INFINITY;
    #pragma unroll
    for (int j = 0; j < NCLS; j++){
      v[j] = part[tid][0][j] + part[tid][1][j] + part[tid][2][j] + part[tid][3][j] + bias[j];
      m = fmaxf(m, v[j]);
    }
    float s = 0.f;
    #pragma unroll
    for (int j = 0; j < NCLS; j++) s += expf(v[j] - m);
    float ls = logf(s) + m;
    #pragma unroll
    for (int j = 0; j < NCLS; j++) out[(size_t)rr*NCLS + j] = v[j] - ls;
  }
}

// ---------------- host ----------------
extern "C" void kernel_launch(void* const* d_in, const int* in_sizes, int n_in,
                              void* d_out, int out_size, void* d_ws, size_t ws_size,
                              hipStream_t stream){
  const float* x    = (const float*)d_in[0];
  const int*   src  = (const int*)d_in[1];
  const int*   dst  = (const int*)d_in[2];
  const int*   batch= (const int*)d_in[3];
  const float* W0   = (const float*)d_in[4];
  const float* Wsm  = (const float*)d_in[5];
  const float* g_bn = (const float*)d_in[7];
  const float* b_bn = (const float*)d_in[8];
  const float* g_out= (const float*)d_in[9];
  const float* b_out= (const float*)d_in[10];
  const float* w1   = (const float*)d_in[11];
  const float* b1   = (const float*)d_in[12];
  const float* w2   = (const float*)d_in[13];
  const float* b2   = (const float*)d_in[14];
  const float* w3   = (const float*)d_in[15];
  const float* b3   = (const float*)d_in[16];

  int n = in_sizes[3];   // N_NODES
  int E = in_sizes[1];   // N_EDGES

  char* ws = (char*)d_ws;
  size_t off = 0;
  auto alloc = [&](size_t bytes) -> char* {
    char* p = ws + off;
    off += (bytes + 255) / 256 * 256;
    return p;
  };
  int*   degi      = (int*)  alloc((size_t)n*4);
  float* normv     = (float*)alloc((size_t)n*4);
  int*   row_start = (int*)  alloc((size_t)(n+1)*4);
  int*   cursor    = (int*)  alloc((size_t)n*4);
  int*   colA      = (int*)  alloc((size_t)E*4);
  int*   bsum      = (int*)  alloc(512*4);
  int*   bcnt      = (int*)  alloc(NB*4);
  int*   bofs      = (int*)  alloc(NB*4);
  int*   bcursor   = (int*)  alloc(NB*4);
  int2*  stage     = (int2*) alloc((size_t)E*8);
  unsigned* U32    = (unsigned*)alloc((size_t)n*32*4);    // packed bf16, 128B/row
  size_t lstride32 = (size_t)n*32;                        // uints per layer buffer
  unsigned* AGGall = (unsigned*)alloc((size_t)NLAYER*lstride32*4);  // bf16 packed
  float* bnsums    = (float*)alloc(8*128*4);
  float* bnss      = (float*)alloc(NLAYER*128*4);         // per-layer [sc(64)|sh(64)]
  float* Ppart     = (float*)alloc((size_t)NG*8*512*4);
  float* Hg        = (float*)alloc((size_t)NG*M3*4);
  float* Z1        = (float*)alloc((size_t)NG*M2*4);
  float* Z2        = (float*)alloc((size_t)NG*M1*4);
  float* zsc       = (float*)alloc(M3*4);
  float* zsh       = (float*)alloc(M3*4);

  int nb256 = (n + 255) / 256;
  int eb256 = (E + 255) / 256;
  int nb_used = (n + 255) >> 8;          // buckets actually populated

  hipMemsetAsync(degi, 0, (size_t)n*4, stream);
  k_deg<<<eb256, 256, 0, stream>>>(dst, E, degi);
  k_norm<<<nb256, 256, 0, stream>>>(degi, normv, n);
  k_scan_a<<<nb256, 256, 0, stream>>>(degi, n, row_start, bsum);
  k_scan_b<<<1, 512, 0, stream>>>(bsum, nb256);
  k_scan_c<<<nb256, 256, 0, stream>>>(row_start, bsum, cursor, n, E);
  k_bcnt_from_deg<<<NB, 256, 0, stream>>>(degi, n, bcnt);
  k_bscan<<<1, NB, 0, stream>>>(bcnt, bofs, bcursor);
  { int tiles = (E + 256*EPT - 1)/(256*EPT);
    k_bscatter<<<tiles, 256, 0, stream>>>(src, dst, E, bcursor, stage); }
  k_fill_b<<<nb_used, 256, 0, stream>>>(stage, bofs, bcnt, cursor, colA);

  float invn = 1.f / (float)n;
  int aggblocks = (n + 4*NPW - 1) / (4*NPW);
  for (int l = 0; l < NLAYER; l++){
    unsigned* AGGb = AGGall + (size_t)l*lstride32;
    if (l == 0)
      k_node_gemm<128><<<nb256, 256, 0, stream>>>(x, 128, W0, normv, U32, n);
    else
      k_node_gemm_b<<<nb256, 256, 0, stream>>>(AGGall + (size_t)(l-1)*lstride32,
                                               Wsm + (size_t)(l-1)*64*64, normv,
                                               bnss + (l-1)*128, U32, n);
    hipMemsetAsync(bnsums, 0, 8*128*4, stream);
    k_agg_bn<<<aggblocks, 256, 0, stream>>>(U32, row_start, colA, normv, AGGb, bnsums, n);
    k_bn_finalize<<<1, 64, 0, stream>>>(bnsums, g_bn + l*64, b_bn + l*64, bnss + l*128, invn);
  }

  k_pool_part<<<NG*8, 256, 0, stream>>>(AGGall, lstride32, bnss, batch, n, Ppart);
  k_pool_comb<<<NG, 256, 0, stream>>>(Ppart, batch, n, Hg);
  k_bn2<<<M3, 64, 0, stream>>>(Hg, g_out, b_out, zsc, zsh);

  { dim3 g1(M2/32, NG/32); k_gemm_t<<<g1, 256, 0, stream>>>(Hg, M3, w1, M2, b1, zsc, zsh, Z1, 1, 1); }
  { dim3 g2(M1/32, NG/32); k_gemm_t<<<g2, 256, 0, stream>>>(Z1, M2, w2, M1, b2, nullptr, nullptr, Z2, 1, 0); }
  k_gemm3_lsm<<<NG/64, 256, 0, stream>>>(Z2, w3, b3, (float*)d_out);
}

// Round 9
// 461.621 us; speedup vs baseline: 6.6039x; 1.2341x over previous
//
#include <hip/hip_runtime.h>
#include <hip/hip_bf16.h>
#include <math.h>

#define HIDC 64
#define NLAYER 4
#define NG 512
#define M3 768
#define M2 512
#define M1 256
#define NCLS 10
#define EPSV 1e-5f
#define NB 512          // partition buckets (dst >> 8), covers n < 131072
#define EPT 16          // edges per thread in scatter tile
#define NPW 4           // nodes per wave in aggregation

// bf16 helpers (packed 2xbf16 in a uint32)
__device__ inline unsigned bf16rne(float x){
  unsigned u = __float_as_uint(x);
  return (u + 0x7fffu + ((u >> 16) & 1u)) >> 16;
}
__device__ inline unsigned packbf2(float lo, float hi){
  return bf16rne(lo) | (bf16rne(hi) << 16);
}
__device__ inline float blo(unsigned u){ return __uint_as_float(u << 16); }
__device__ inline float bhi(unsigned u){ return __uint_as_float(u & 0xffff0000u); }

// ---------------- graph build ----------------
// 512-bin LDS histogram of dst>>8 -> bucket counts
__global__ __launch_bounds__(256) void k_bhist(const int* __restrict__ dst, int E,
                                               int* __restrict__ bcnt){
  __shared__ int lc[NB];
  int tid = threadIdx.x;
  for (int i = tid; i < NB; i += 256) lc[i] = 0;
  __syncthreads();
  for (int e = blockIdx.x*256 + tid; e < E; e += gridDim.x*256)
    atomicAdd(&lc[__builtin_nontemporal_load(&dst[e]) >> 8], 1);
  __syncthreads();
  for (int i = tid; i < NB; i += 256){
    int c = lc[i];
    if (c) atomicAdd(&bcnt[i], c);
  }
}

__global__ void k_bscan(const int* __restrict__ bcnt, int* __restrict__ bofs,
                        int* __restrict__ bcursor){
  __shared__ int tmp[NB];
  int tid = threadIdx.x;       // 512 threads
  int v = bcnt[tid];
  tmp[tid] = v; __syncthreads();
  for (int ofs = 1; ofs < NB; ofs <<= 1){
    int t = (tid >= ofs) ? tmp[tid-ofs] : 0;
    __syncthreads();
    tmp[tid] += t;
    __syncthreads();
  }
  int ex = tmp[tid] - v;
  bofs[tid] = ex;
  bcursor[tid] = ex;
}

// Each block: LDS histogram of its 4096-edge tile, ONE global atomic per
// (block,bucket) to reserve a contiguous sub-range, then append pairs.
__global__ __launch_bounds__(256) void k_bscatter(const int* __restrict__ src,
    const int* __restrict__ dst, int E, int* __restrict__ bcursor, int2* __restrict__ stage){
  __shared__ int lcnt[NB];
  __shared__ int lbase[NB];
  int tid = threadIdx.x;
  int t0 = blockIdx.x*(256*EPT);
  for (int i = tid; i < NB; i += 256) lcnt[i] = 0;
  __syncthreads();
  int s_[EPT], d_[EPT];
  bool ok[EPT];
  #pragma unroll
  for (int i = 0; i < EPT; i++){
    int e = t0 + i*256 + tid;
    ok[i] = (e < E);
    int ee = ok[i] ? e : 0;
    d_[i] = __builtin_nontemporal_load(&dst[ee]);
    s_[i] = __builtin_nontemporal_load(&src[ee]);
    if (ok[i]) atomicAdd(&lcnt[d_[i] >> 8], 1);
  }
  __syncthreads();
  for (int i = tid; i < NB; i += 256){
    int c = lcnt[i];
    lbase[i] = c ? atomicAdd(&bcursor[i], c) : 0;
  }
  __syncthreads();
  #pragma unroll
  for (int i = 0; i < EPT; i++){
    if (ok[i]){
      int pos = atomicAdd(&lbase[d_[i] >> 8], 1);
      stage[pos] = make_int2(s_[i], d_[i]);
    }
  }
}

// One block per bucket: 256-bin LDS degree histogram (NO global atomics; r8
// post-mortem: k_deg's 1.6M device-scope atomic RMWs wrote 50MB to HBM),
// fused intra-bucket exclusive scan -> row_start/cursor (global offset =
// bofs[bucket] + intra-bucket scan) and norm. Replaces k_deg/k_norm/k_scan_*.
__global__ __launch_bounds__(256) void k_deg_b(const int2* __restrict__ stage,
    const int* __restrict__ bofs, const int* __restrict__ bcnt,
    int* __restrict__ row_start, int* __restrict__ cursor,
    float* __restrict__ normv, int n, int E){
  __shared__ int hist[256];
  __shared__ int tmp[256];
  int b = blockIdx.x;
  int tid = threadIdx.x;
  hist[tid] = 0;
  __syncthreads();
  int st = bofs[b], en = st + bcnt[b];
  for (int i = st + tid; i < en; i += 256)
    atomicAdd(&hist[stage[i].y & 255], 1);
  __syncthreads();
  int v = hist[tid];
  tmp[tid] = v;
  __syncthreads();
  for (int o = 1; o < 256; o <<= 1){
    int t = (tid >= o) ? tmp[tid-o] : 0;
    __syncthreads();
    tmp[tid] += t;
    __syncthreads();
  }
  int node = b*256 + tid;
  if (node < n){
    int rs = st + tmp[tid] - v;
    row_start[node] = rs;
    cursor[node] = rs;
    normv[node] = rsqrtf((float)(v + 1));
  }
  if (b == 0 && tid == 0) row_start[n] = E;
}

// One block per bucket: CSR fill confined to the bucket's ~16KB col region.
__global__ __launch_bounds__(256) void k_fill_b(const int2* __restrict__ stage,
    const int* __restrict__ bofs, const int* __restrict__ bcnt,
    int* __restrict__ cursor, int* __restrict__ col){
  int b = blockIdx.x;
  int st = bofs[b], en = st + bcnt[b];
  for (int i = st + threadIdx.x; i < en; i += 256){
    int2 p = stage[i];
    int pos = atomicAdd(&cursor[p.y], 1);
    col[pos] = p.x;
  }
}

// ---------------- node GEMM layer 0: U(bf16) = (x @ W0) * norm[row] ----------------
// 128-row x 64-ch block tile; thread = 4 rows x 8 ch (32 acc). W full in LDS,
// A staged per 32-K chunk (stride 36 keeps float4 alignment, <=4-way conflicts).
// 12 x b128 LDS per 128 FMA -> VALU-bound (r8: old layout was 4B/FMA, LDS-bound).
__global__ __launch_bounds__(256) void k_gemm_l0(const float* __restrict__ A,
    const float* __restrict__ W, const float* __restrict__ norm,
    unsigned* __restrict__ U32, int n){
  __shared__ float Wl[128*64];   // 32KB [k][c]
  __shared__ float Al[128*36];   // 18KB [r][kk], stride 36
  int tid = threadIdx.x;
  {
    const float4* W4 = (const float4*)W;
    float4* Wl4 = (float4*)Wl;
    for (int i = tid; i < 128*16; i += 256) Wl4[i] = W4[i];
  }
  int rb = blockIdx.x * 128;
  int cg = tid & 7;        // channels cg*8 .. cg*8+8
  int rg = tid >> 3;       // rows rg*4 .. rg*4+4 (local)
  float acc[4][8];
  #pragma unroll
  for (int i = 0; i < 4; i++)
    #pragma unroll
    for (int c = 0; c < 8; c++) acc[i][c] = 0.f;
  for (int kc = 0; kc < 128; kc += 32){
    __syncthreads();
    { // stage A chunk: 128 rows x 32 cols
      int r = tid >> 1, h = tid & 1;
      int rr = rb + r; if (rr >= n) rr = 0;
      const float* Ag = A + (size_t)rr*128 + kc + h*16;
      float4 v0 = *(const float4*)(Ag+0);
      float4 v1 = *(const float4*)(Ag+4);
      float4 v2 = *(const float4*)(Ag+8);
      float4 v3 = *(const float4*)(Ag+12);
      float* dl = &Al[r*36 + h*16];
      *(float4*)(dl+0) = v0; *(float4*)(dl+4) = v1;
      *(float4*)(dl+8) = v2; *(float4*)(dl+12) = v3;
    }
    __syncthreads();
    #pragma unroll
    for (int kk = 0; kk < 32; kk += 4){
      float4 a0 = *(const float4*)&Al[(rg*4+0)*36 + kk];
      float4 a1 = *(const float4*)&Al[(rg*4+1)*36 + kk];
      float4 a2 = *(const float4*)&Al[(rg*4+2)*36 + kk];
      float4 a3 = *(const float4*)&Al[(rg*4+3)*36 + kk];
      float ar[4][4] = {{a0.x,a0.y,a0.z,a0.w},{a1.x,a1.y,a1.z,a1.w},
                        {a2.x,a2.y,a2.z,a2.w},{a3.x,a3.y,a3.z,a3.w}};
      #pragma unroll
      for (int j = 0; j < 4; j++){
        const float* wr = &Wl[(kc+kk+j)*64 + cg*8];
        float4 w0 = *(const float4*)(wr);
        float4 w1 = *(const float4*)(wr+4);
        float wv[8] = {w0.x,w0.y,w0.z,w0.w,w1.x,w1.y,w1.z,w1.w};
        #pragma unroll
        for (int i = 0; i < 4; i++)
          #pragma unroll
          for (int c = 0; c < 8; c++)
            acc[i][c] += ar[i][j]*wv[c];
      }
    }
  }
  #pragma unroll
  for (int i = 0; i < 4; i++){
    int r = rb + rg*4 + i;
    if (r < n){
      float nr = norm[r];
      uint4 o;
      o.x = packbf2(acc[i][0]*nr, acc[i][1]*nr);
      o.y = packbf2(acc[i][2]*nr, acc[i][3]*nr);
      o.z = packbf2(acc[i][4]*nr, acc[i][5]*nr);
      o.w = packbf2(acc[i][6]*nr, acc[i][7]*nr);
      *(uint4*)(U32 + (size_t)r*32 + cg*4) = o;
    }
  }
}

// ---------------- node GEMM layers 1+: A bf16-packed, BN applied on staging ------
__global__ __launch_bounds__(256) void k_gemm_lb(const unsigned* __restrict__ Ab,
    const float* __restrict__ W, const float* __restrict__ norm,
    const float* __restrict__ scsh, unsigned* __restrict__ U32, int n){
  __shared__ float Wl[64*64];    // 16KB
  __shared__ float Al[128*36];   // 18KB
  __shared__ float ss[128];
  int tid = threadIdx.x;
  {
    const float4* W4 = (const float4*)W;
    float4* Wl4 = (float4*)Wl;
    for (int i = tid; i < 64*16; i += 256) Wl4[i] = W4[i];
  }
  if (tid < 128) ss[tid] = scsh[tid];
  int rb = blockIdx.x * 128;
  int cg = tid & 7;
  int rg = tid >> 3;
  float acc[4][8];
  #pragma unroll
  for (int i = 0; i < 4; i++)
    #pragma unroll
    for (int c = 0; c < 8; c++) acc[i][c] = 0.f;
  for (int kc = 0; kc < 64; kc += 32){
    __syncthreads();
    { // stage A chunk with BN: 128 rows x 32 k-values (= 16 packed uints)
      int r = tid >> 1, h = tid & 1;
      int rr = rb + r; if (rr >= n) rr = 0;
      const uint4* Ag = (const uint4*)(Ab + (size_t)rr*32 + (kc >> 1) + h*8);
      uint4 u0 = Ag[0], u1 = Ag[1];
      int kl = h*16;
      int kg = kc + kl;
      float f[16];
      f[0]=blo(u0.x); f[1]=bhi(u0.x); f[2]=blo(u0.y); f[3]=bhi(u0.y);
      f[4]=blo(u0.z); f[5]=bhi(u0.z); f[6]=blo(u0.w); f[7]=bhi(u0.w);
      f[8]=blo(u1.x); f[9]=bhi(u1.x); f[10]=blo(u1.y); f[11]=bhi(u1.y);
      f[12]=blo(u1.z); f[13]=bhi(u1.z); f[14]=blo(u1.w); f[15]=bhi(u1.w);
      #pragma unroll
      for (int j = 0; j < 16; j++) f[j] = f[j]*ss[kg+j] + ss[64+kg+j];
      float* dl = &Al[r*36 + kl];
      *(float4*)(dl+0)  = make_float4(f[0],f[1],f[2],f[3]);
      *(float4*)(dl+4)  = make_float4(f[4],f[5],f[6],f[7]);
      *(float4*)(dl+8)  = make_float4(f[8],f[9],f[10],f[11]);
      *(float4*)(dl+12) = make_float4(f[12],f[13],f[14],f[15]);
    }
    __syncthreads();
    #pragma unroll
    for (int kk = 0; kk < 32; kk += 4){
      float4 a0 = *(const float4*)&Al[(rg*4+0)*36 + kk];
      float4 a1 = *(const float4*)&Al[(rg*4+1)*36 + kk];
      float4 a2 = *(const float4*)&Al[(rg*4+2)*36 + kk];
      float4 a3 = *(const float4*)&Al[(rg*4+3)*36 + kk];
      float ar[4][4] = {{a0.x,a0.y,a0.z,a0.w},{a1.x,a1.y,a1.z,a1.w},
                        {a2.x,a2.y,a2.z,a2.w},{a3.x,a3.y,a3.z,a3.w}};
      #pragma unroll
      for (int j = 0; j < 4; j++){
        const float* wr = &Wl[(kc+kk+j)*64 + cg*8];
        float4 w0 = *(const float4*)(wr);
        float4 w1 = *(const float4*)(wr+4);
        float wv[8] = {w0.x,w0.y,w0.z,w0.w,w1.x,w1.y,w1.z,w1.w};
        #pragma unroll
        for (int i = 0; i < 4; i++)
          #pragma unroll
          for (int c = 0; c < 8; c++)
            acc[i][c] += ar[i][j]*wv[c];
      }
    }
  }
  #pragma unroll
  for (int i = 0; i < 4; i++){
    int r = rb + rg*4 + i;
    if (r < n){
      float nr = norm[r];
      uint4 o;
      o.x = packbf2(acc[i][0]*nr, acc[i][1]*nr);
      o.y = packbf2(acc[i][2]*nr, acc[i][3]*nr);
      o.z = packbf2(acc[i][4]*nr, acc[i][5]*nr);
      o.w = packbf2(acc[i][6]*nr, acc[i][7]*nr);
      *(uint4*)(U32 + (size_t)r*32 + cg*4) = o;
    }
  }
}

// ---------------- aggregation + fused BN stats ----------------
// One node per wave; NPW nodes sequentially per wave; two 32-lane halves handle
// different edges; all iterations full-width masked (no serial tail).
__global__ __launch_bounds__(256) void k_agg_bn(const unsigned* __restrict__ U32,
    const int* __restrict__ row_start, const int* __restrict__ col,
    const float* __restrict__ norm, unsigned* __restrict__ AGGb,
    float* __restrict__ sums8, int n){
  int tid = threadIdx.x;
  int wv = tid >> 6;
  int lane = tid & 63;
  int half = lane >> 5;
  int cl = lane & 31;
  float rs0=0.f, rs1=0.f, rq0=0.f, rq1=0.f;
  int base = blockIdx.x*(4*NPW) + wv*NPW;
  #pragma unroll
  for (int it = 0; it < NPW; ++it){
    int node = __builtin_amdgcn_readfirstlane(base + it);
    bool nv = (node < n);
    int nodec = nv ? node : 0;
    int st = row_start[nodec], en = row_start[nodec+1];
    float s0 = 0.f, s1 = 0.f;
    if (half == 0){
      unsigned u = U32[(size_t)nodec*32 + cl];
      s0 = blo(u); s1 = bhi(u);
    }
    int nit = (en - st + 15) >> 4;
    for (int i = 0; i < nit; i++){
      int k = st + i*16 + half*8;
      unsigned ua[8]; float m[8];
      #pragma unroll
      for (int j = 0; j < 8; j++){
        int kk = k + j;
        bool v = (kk < en);
        int idx = v ? kk : st;
        int jn = col[idx];
        ua[j] = U32[(size_t)jn*32 + cl];
        m[j] = v ? 1.f : 0.f;
      }
      #pragma unroll
      for (int j = 0; j < 8; j++){
        s0 += m[j]*blo(ua[j]);
        s1 += m[j]*bhi(ua[j]);
      }
    }
    s0 += __shfl_xor(s0, 32);
    s1 += __shfl_xor(s1, 32);
    if (half == 0 && nv){
      float nr = norm[node];
      s0 *= nr; s1 *= nr;
      AGGb[(size_t)node*32 + cl] = packbf2(s0, s1);
      rs0 += s0; rs1 += s1; rq0 += s0*s0; rq1 += s1*s1;
    }
  }
  __shared__ float L[4][32][4];
  if (half == 0){ L[wv][cl][0]=rs0; L[wv][cl][1]=rs1; L[wv][cl][2]=rq0; L[wv][cl][3]=rq1; }
  __syncthreads();
  if (tid < 128){
    int c2 = tid & 31, f = tid >> 5;
    float v = L[0][c2][f] + L[1][c2][f] + L[2][c2][f] + L[3][c2][f];
    int addr = ((f >= 2) ? 64 : 0) + 2*c2 + (f & 1);
    atomicAdd(&sums8[(blockIdx.x & 7)*128 + addr], v);
  }
}

// ---------------- batchnorm finalize: per-layer scale/shift ----------------
__global__ void k_bn_finalize(const float* __restrict__ sums8, const float* __restrict__ g,
                              const float* __restrict__ b, float* __restrict__ scsh, float invn){
  int c = threadIdx.x;
  float s1 = 0.f, s2 = 0.f;
  #pragma unroll
  for (int s = 0; s < 8; s++){ s1 += sums8[s*128 + c]; s2 += sums8[s*128 + 64 + c]; }
  float mean = s1*invn;
  float var = s2*invn - mean*mean;
  var = fmaxf(var, 0.f);
  float sv = g[c]*rsqrtf(var + EPSV);
  scsh[c] = sv;
  scsh[64 + c] = b[c] - mean*sv;
}

// ---------------- pooling, split 8x in the row dimension (bf16 AGG input) -------
__device__ inline int lowerb(const int* a, int n, int key){
  int lo = 0, hi = n;
  while (lo < hi){ int mid = (lo+hi) >> 1; if (a[mid] < key) lo = mid+1; else hi = mid; }
  return lo;
}

__global__ __launch_bounds__(256) void k_pool_part(const unsigned* __restrict__ AGGall,
    size_t lstride32, const float* __restrict__ bnss, const int* __restrict__ batch,
    int n, float* __restrict__ Ppart){
  int bid = blockIdx.x;
  int g = bid >> 3, sub = bid & 7;
  int c = threadIdx.x;
  int l = c >> 6, ch = c & 63;
  const unsigned* A = AGGall + (size_t)l * lstride32;
  float sc = bnss[l*128 + ch], sh = bnss[l*128 + 64 + ch];
  int hi16 = ch & 1;
  int uofs = ch >> 1;
  int st = lowerb(batch, n, g), en = lowerb(batch, n, g+1);
  int len = en - st;
  int r0 = st + (int)(((long long)sub * len) >> 3);
  int r1 = st + (int)(((long long)(sub+1) * len) >> 3);
  float s = 0.f, mx = -INFINITY;
  for (int r = r0; r < r1; r++){
    unsigned u = A[(size_t)r*32 + uofs];
    float v = hi16 ? bhi(u) : blo(u);
    v = v*sc + sh;
    s += v; mx = fmaxf(mx, v);
  }
  float* P = Ppart + (size_t)bid*512;
  P[c] = s;
  P[256 + c] = mx;
}

__global__ __launch_bounds__(256) void k_pool_comb(const float* __restrict__ Ppart,
    const int* __restrict__ batch, int n, float* __restrict__ Hg){
  int g = blockIdx.x; int c = threadIdx.x;
  float s = 0.f, mx = -INFINITY;
  #pragma unroll
  for (int sub = 0; sub < 8; sub++){
    const float* P = Ppart + (size_t)(g*8 + sub)*512;
    s += P[c];
    mx = fmaxf(mx, P[256 + c]);
  }
  int st = lowerb(batch, n, g), en = lowerb(batch, n, g+1);
  int cnt = en - st;
  float avg = s / (float)(cnt > 1 ? cnt : 1);
  float mo = (cnt > 0) ? mx : 0.f;
  Hg[(size_t)g*M3 + c]        = avg;
  Hg[(size_t)g*M3 + 256 + c]  = s;
  Hg[(size_t)g*M3 + 512 + c]  = mo;
}

// ---------------- readout BN (stats -> scale/shift) ----------------
__global__ void k_bn2(const float* __restrict__ Hg, const float* __restrict__ g,
                      const float* __restrict__ b, float* __restrict__ zsc, float* __restrict__ zsh){
  int c = blockIdx.x; int tid = threadIdx.x;  // 64 threads
  float s1 = 0.f, s2 = 0.f;
  for (int r = tid; r < NG; r += 64){
    float v = Hg[(size_t)r*M3 + c];
    s1 += v; s2 += v*v;
  }
  for (int o = 32; o > 0; o >>= 1){ s1 += __shfl_down(s1, o); s2 += __shfl_down(s2, o); }
  if (tid == 0){
    float mean = s1/(float)NG;
    float var = s2/(float)NG - mean*mean;
    var = fmaxf(var, 0.f);
    float sc = g[c]*rsqrtf(var + EPSV);
    zsc[c] = sc;
    zsh[c] = b[c] - mean*sc;
  }
}

// ---------------- tiled readout GEMM (32x32 tile, 2x2/thread) ----------------
__global__ __launch_bounds__(256) void k_gemm_t(const float* __restrict__ A, int K,
    const float* __restrict__ W, int N, const float* __restrict__ bias,
    const float* __restrict__ zsc, const float* __restrict__ zsh,
    float* __restrict__ out, int relu, int applybn){
  __shared__ float As[32][36];
  __shared__ float Bs[32][36];   // transposed: Bs[n][k]
  int tid = threadIdx.x;
  int tx = tid & 15, ty = tid >> 4;
  int rb = blockIdx.y << 5, cb = blockIdx.x << 5;
  int lr = tid >> 3;            // 0..31
  int lk = (tid & 7) << 2;      // 0,4,...,28
  float acc00=0.f, acc01=0.f, acc10=0.f, acc11=0.f;
  for (int k0 = 0; k0 < K; k0 += 32){
    float4 av = *(const float4*)&A[(size_t)(rb+lr)*K + k0 + lk];
    if (applybn){
      av.x = av.x*zsc[k0+lk+0] + zsh[k0+lk+0];
      av.y = av.y*zsc[k0+lk+1] + zsh[k0+lk+1];
      av.z = av.z*zsc[k0+lk+2] + zsh[k0+lk+2];
      av.w = av.w*zsc[k0+lk+3] + zsh[k0+lk+3];
    }
    *(float4*)&As[lr][lk] = av;
    float4 bv = *(const float4*)&W[(size_t)(k0+lr)*N + cb + lk];
    Bs[lk+0][lr] = bv.x;
    Bs[lk+1][lr] = bv.y;
    Bs[lk+2][lr] = bv.z;
    Bs[lk+3][lr] = bv.w;
    __syncthreads();
    #pragma unroll
    for (int kk = 0; kk < 32; kk += 4){
      float4 a0 = *(const float4*)&As[ty][kk];
      float4 a1 = *(const float4*)&As[ty+16][kk];
      float4 b0 = *(const float4*)&Bs[tx][kk];
      float4 b1 = *(const float4*)&Bs[tx+16][kk];
      acc00 += a0.x*b0.x + a0.y*b0.y + a0.z*b0.z + a0.w*b0.w;
      acc01 += a0.x*b1.x + a0.y*b1.y + a0.z*b1.z + a0.w*b1.w;
      acc10 += a1.x*b0.x + a1.y*b0.y + a1.z*b0.z + a1.w*b0.w;
      acc11 += a1.x*b1.x + a1.y*b1.y + a1.z*b1.z + a1.w*b1.w;
    }
    __syncthreads();
  }
  int c0 = cb + tx, c1 = cb + tx + 16;
  float bz0 = bias[c0], bz1 = bias[c1];
  acc00 += bz0; acc01 += bz1; acc10 += bz0; acc11 += bz1;
  if (relu){
    acc00 = fmaxf(acc00, 0.f); acc01 = fmaxf(acc01, 0.f);
    acc10 = fmaxf(acc10, 0.f); acc11 = fmaxf(acc11, 0.f);
  }
  out[(size_t)(rb+ty)*N + c0]      = acc00;
  out[(size_t)(rb+ty)*N + c1]      = acc01;
  out[(size_t)(rb+ty+16)*N + c0]   = acc10;
  out[(size_t)(rb+ty+16)*N + c1]   = acc11;
}

// ---------------- final tiny GEMM (K=256, N=10) fused with log-softmax --------
__global__ __launch_bounds__(256) void k_gemm3_lsm(const float* __restrict__ A,
    const float* __restrict__ W, const float* __restrict__ bias, float* __restrict__ out){
  __shared__ float Wl[M1*NCLS];       // 10 KB
  __shared__ float part[64][4][NCLS]; // 10 KB
  int tid = threadIdx.x;
  for (int i = tid; i < M1*NCLS; i += 256) Wl[i] = W[i];
  __syncthreads();
  int r = blockIdx.x*64 + (tid >> 2);
  int q = tid & 3;
  float acc[NCLS];
  #pragma unroll
  for (int j = 0; j < NCLS; j++) acc[j] = 0.f;
  const float4* A4 = (const float4*)(A + (size_t)r*M1 + q*64);
  for (int kq = 0; kq < 16; kq++){
    float4 a = A4[kq];
    int kb = q*64 + kq*4;
    #pragma unroll
    for (int j = 0; j < NCLS; j++){
      acc[j] += a.x*Wl[(kb+0)*NCLS+j] + a.y*Wl[(kb+1)*NCLS+j]
              + a.z*Wl[(kb+2)*NCLS+j] + a.w*Wl[(kb+3)*NCLS+j];
    }
  }
  #pragma unroll
  for (int j = 0; j < NCLS; j++) part[tid>>2][q][j] = acc[j];
  __syncthreads();
  if (tid < 64){
    int rr = blockIdx.x*64 + tid;
    float v[NCLS]; float m = -INFINITY;
    #pragma unroll
    for (int j = 0; j < NCLS; j++){
      v[j] = part[tid][0][j] + part[tid][1][j] + part[tid][2][j] + part[tid][3][j] + bias[j];
      m = fmaxf(m, v[j]);
    }
    float s = 0.f;
    #pragma unroll
    for (int j = 0; j < NCLS; j++) s += expf(v[j] - m);
    float ls = logf(s) + m;
    #pragma unroll
    for (int j = 0; j < NCLS; j++) out[(size_t)rr*NCLS + j] = v[j] - ls;
  }
}

// ---------------- host ----------------
extern "C" void kernel_launch(void* const* d_in, const int* in_sizes, int n_in,
                              void* d_out, int out_size, void* d_ws, size_t ws_size,
                              hipStream_t stream){
  const float* x    = (const float*)d_in[0];
  const int*   src  = (const int*)d_in[1];
  const int*   dst  = (const int*)d_in[2];
  const int*   batch= (const int*)d_in[3];
  const float* W0   = (const float*)d_in[4];
  const float* Wsm  = (const float*)d_in[5];
  const float* g_bn = (const float*)d_in[7];
  const float* b_bn = (const float*)d_in[8];
  const float* g_out= (const float*)d_in[9];
  const float* b_out= (const float*)d_in[10];
  const float* w1   = (const float*)d_in[11];
  const float* b1   = (const float*)d_in[12];
  const float* w2   = (const float*)d_in[13];
  const float* b2   = (const float*)d_in[14];
  const float* w3   = (const float*)d_in[15];
  const float* b3   = (const float*)d_in[16];

  int n = in_sizes[3];   // N_NODES
  int E = in_sizes[1];   // N_EDGES

  char* ws = (char*)d_ws;
  size_t off = 0;
  auto alloc = [&](size_t bytes) -> char* {
    char* p = ws + off;
    off += (bytes + 255) / 256 * 256;
    return p;
  };
  float* normv     = (float*)alloc((size_t)n*4);
  int*   row_start = (int*)  alloc((size_t)(n+1)*4);
  int*   cursor    = (int*)  alloc((size_t)n*4);
  int*   colA      = (int*)  alloc((size_t)E*4);
  int*   bcnt      = (int*)  alloc(NB*4);
  int*   bofs      = (int*)  alloc(NB*4);
  int*   bcursor   = (int*)  alloc(NB*4);
  int2*  stage     = (int2*) alloc((size_t)E*8);
  unsigned* U32    = (unsigned*)alloc((size_t)n*32*4);    // packed bf16, 128B/row
  size_t lstride32 = (size_t)n*32;                        // uints per layer buffer
  unsigned* AGGall = (unsigned*)alloc((size_t)NLAYER*lstride32*4);  // bf16 packed
  float* bnsums    = (float*)alloc(8*128*4);
  float* bnss      = (float*)alloc(NLAYER*128*4);         // per-layer [sc(64)|sh(64)]
  float* Ppart     = (float*)alloc((size_t)NG*8*512*4);
  float* Hg        = (float*)alloc((size_t)NG*M3*4);
  float* Z1        = (float*)alloc((size_t)NG*M2*4);
  float* Z2        = (float*)alloc((size_t)NG*M1*4);
  float* zsc       = (float*)alloc(M3*4);
  float* zsh       = (float*)alloc(M3*4);

  int nb_used = (n + 255) >> 8;          // buckets actually populated
  int gb = (n + 127) / 128;              // node-GEMM grid

  hipMemsetAsync(bcnt, 0, NB*4, stream);
  k_bhist<<<512, 256, 0, stream>>>(dst, E, bcnt);
  k_bscan<<<1, NB, 0, stream>>>(bcnt, bofs, bcursor);
  { int tiles = (E + 256*EPT - 1)/(256*EPT);
    k_bscatter<<<tiles, 256, 0, stream>>>(src, dst, E, bcursor, stage); }
  k_deg_b<<<nb_used, 256, 0, stream>>>(stage, bofs, bcnt, row_start, cursor, normv, n, E);
  k_fill_b<<<nb_used, 256, 0, stream>>>(stage, bofs, bcnt, cursor, colA);

  float invn = 1.f / (float)n;
  int aggblocks = (n + 4*NPW - 1) / (4*NPW);
  for (int l = 0; l < NLAYER; l++){
    unsigned* AGGb = AGGall + (size_t)l*lstride32;
    if (l == 0)
      k_gemm_l0<<<gb, 256, 0, stream>>>(x, W0, normv, U32, n);
    else
      k_gemm_lb<<<gb, 256, 0, stream>>>(AGGall + (size_t)(l-1)*lstride32,
                                        Wsm + (size_t)(l-1)*64*64, normv,
                                        bnss + (l-1)*128, U32, n);
    hipMemsetAsync(bnsums, 0, 8*128*4, stream);
    k_agg_bn<<<aggblocks, 256, 0, stream>>>(U32, row_start, colA, normv, AGGb, bnsums, n);
    k_bn_finalize<<<1, 64, 0, stream>>>(bnsums, g_bn + l*64, b_bn + l*64, bnss + l*128, invn);
  }

  k_pool_part<<<NG*8, 256, 0, stream>>>(AGGall, lstride32, bnss, batch, n, Ppart);
  k_pool_comb<<<NG, 256, 0, stream>>>(Ppart, batch, n, Hg);
  k_bn2<<<M3, 64, 0, stream>>>(Hg, g_out, b_out, zsc, zsh);

  { dim3 g1(M2/32, NG/32); k_gemm_t<<<g1, 256, 0, stream>>>(Hg, M3, w1, M2, b1, zsc, zsh, Z1, 1, 1); }
  { dim3 g2(M1/32, NG/32); k_gemm_t<<<g2, 256, 0, stream>>>(Z1, M2, w2, M1, b2, nullptr, nullptr, Z2, 1, 0); }
  k_gemm3_lsm<<<NG/64, 256, 0, stream>>>(Z2, w3, b3, (float*)d_out);
}